// Round 1
// baseline (797.028 us; speedup 1.0000x reference)
//
#include <hip/hip_runtime.h>
#include <hip/hip_bf16.h>
#include <math.h>

#define BB 2
#define LL 160
#define NSC 34
#define NS (LL * NSC)      // 5440
#define AD 128
#define HID 512
#define NAT 37

// ---------------- K1: prep ----------------
// grid = B*L blocks, 128 threads
__global__ __launch_bounds__(128) void k_prep(
    const float* __restrict__ bb, const float* __restrict__ sf,
    const float* __restrict__ aa, const float* __restrict__ mask,
    const float* __restrict__ pm, const float* __restrict__ emb,
    const float* __restrict__ noise,
    float* __restrict__ out_mask, float4* __restrict__ ws_x,
    float* __restrict__ ws_hf) {
  int bl = blockIdx.x;                 // b*L + l
  int b = bl / LL, l = bl % LL;
  int tid = threadIdx.x;

  // argmax over 20 (first max wins, matches jnp.argmax)
  const float* ap = aa + bl * 20;
  float mv = ap[0]; int rt = 0;
  for (int r = 1; r < 20; ++r) { float v = ap[r]; if (v > mv) { mv = v; rt = r; } }
  float mk = mask[bl];
  const float* pmr = pm + rt * NAT;

  if (tid < NAT) out_mask[bl * NAT + tid] = pmr[tid] * mk;

  float ca0 = bb[(bl * 3 + 1) * 3 + 0] * mk;
  float ca1 = bb[(bl * 3 + 1) * 3 + 1] * mk;
  float ca2 = bb[(bl * 3 + 1) * 3 + 2] * mk;

  if (tid < NSC) {
    int s = tid;
    float am = pmr[3 + s] * mk;
    const float* np = noise + (bl * NSC + s) * 3;
    float4 xv;
    xv.x = ca0 + np[0]; xv.y = ca1 + np[1]; xv.z = ca2 + np[2]; xv.w = am;
    ws_x[b * NS + l * NSC + s] = xv;
  }

  float sv = sf[(size_t)bl * AD + tid];   // tid in [0,128)
  for (int s = 0; s < NSC; ++s) {
    float am = pmr[3 + s] * mk;
    ws_hf[((size_t)(b * NS + l * NSC + s)) * AD + tid] =
        (sv + emb[(3 + s) * AD + tid] * am) * am;
  }
}

// ---------------- K2: deg / w@x  (wave per row) ----------------
// grid = B*NS/4 blocks, 256 threads (4 waves)
__global__ __launch_bounds__(256) void k_degwx(
    const float4* __restrict__ ws_x, float4* __restrict__ ws_ap) {
  int w = threadIdx.x >> 6, lane = threadIdx.x & 63;
  int gid = blockIdx.x * 4 + w;        // b*NS + n
  int b = gid / NS;
  float4 xn = ws_x[gid];
  float x2n = xn.x * xn.x + xn.y * xn.y + xn.z * xn.z;
  float deg = 0.f, wx0 = 0.f, wx1 = 0.f, wx2 = 0.f;
  const float4* xb = ws_x + b * NS;
  for (int m = lane; m < NS; m += 64) {
    float4 xm = xb[m];
    float x2m = xm.x * xm.x + xm.y * xm.y + xm.z * xm.z;
    float dt = xn.x * xm.x + xn.y * xm.y + xn.z * xm.z;
    float d2 = x2n + x2m - 2.f * dt;
    if (d2 < 64.f) {
      float wv = __expf(d2 * -0.0078125f) * (xn.w * xm.w);
      deg += wv; wx0 += wv * xm.x; wx1 += wv * xm.y; wx2 += wv * xm.z;
    }
  }
  #pragma unroll
  for (int o = 32; o; o >>= 1) {
    deg += __shfl_xor(deg, o); wx0 += __shfl_xor(wx0, o);
    wx1 += __shfl_xor(wx1, o); wx2 += __shfl_xor(wx2, o);
  }
  if (lane == 0) {
    float inv = 1.f / (deg + 1.f);
    float4 r;
    r.x = (xn.x * deg - wx0) * inv;
    r.y = (xn.y * deg - wx1) * inv;
    r.z = (xn.z * deg - wx2) * inv;
    r.w = inv;
    ws_ap[gid] = r;
  }
}

// ---------------- K3: h_agg = (w @ hf) * inv ----------------
// grid = B * 170 blocks (32 rows each), 256 threads
// thread = (chgrp 0..15 -> 8 channels, rowgrp 0..15 -> 2 rows)
#define SWST 68   // padded w-tile stride (68*4B = 272B, 16B aligned, bank-shifted)
__global__ __launch_bounds__(256) void k_hagg(
    const float4* __restrict__ ws_x, const float* __restrict__ ws_hf,
    const float4* __restrict__ ws_ap, float* __restrict__ ws_hagg) {
  __shared__ float4 sxn[32];
  __shared__ float4 sxm[64];
  __shared__ float  sw[32 * SWST];

  int tile = blockIdx.x % 170, b = blockIdx.x / 170;
  int n0 = tile * 32;
  int tid = threadIdx.x;
  int chgrp = tid & 15, rg = tid >> 4;
  int c0 = chgrp * 8;

  const float4* xb = ws_x + b * NS;
  if (tid < 32) sxn[tid] = xb[n0 + tid];

  float acc[2][8];
  #pragma unroll
  for (int r = 0; r < 2; ++r)
    #pragma unroll
    for (int c = 0; c < 8; ++c) acc[r][c] = 0.f;

  const float* hfb = ws_hf + ((size_t)b * NS) * AD;

  for (int mbase = 0; mbase < NS; mbase += 64) {
    __syncthreads();                       // prev phase-B readers done
    if (tid < 64) sxm[tid] = xb[mbase + tid];
    __syncthreads();
    // phase A: w tile 32x64
    #pragma unroll
    for (int k = 0; k < 8; ++k) {
      int idx = tid + k * 256;
      int row = idx >> 6, m = idx & 63;
      float4 xn = sxn[row], xm = sxm[m];
      float x2n = xn.x * xn.x + xn.y * xn.y + xn.z * xn.z;
      float x2m = xm.x * xm.x + xm.y * xm.y + xm.z * xm.z;
      float dt  = xn.x * xm.x + xn.y * xm.y + xn.z * xm.z;
      float d2 = x2n + x2m - 2.f * dt;
      float wv = 0.f;
      if (d2 < 64.f) wv = __expf(d2 * -0.0078125f) * (xn.w * xm.w);
      sw[row * SWST + m] = wv;
    }
    __syncthreads();
    // phase B: accumulate
    const float* hfm = hfb + (size_t)mbase * AD + c0;
    for (int mq = 0; mq < 16; ++mq) {
      float4 ha[4], hb[4];
      #pragma unroll
      for (int j = 0; j < 4; ++j) {
        const float* p = hfm + (mq * 4 + j) * AD;
        ha[j] = *(const float4*)p;
        hb[j] = *(const float4*)(p + 4);
      }
      #pragma unroll
      for (int rr = 0; rr < 2; ++rr) {
        int row = rg + rr * 16;
        float4 wq = *(const float4*)&sw[row * SWST + mq * 4];
        float wv[4] = {wq.x, wq.y, wq.z, wq.w};
        #pragma unroll
        for (int j = 0; j < 4; ++j) {
          acc[rr][0] += wv[j] * ha[j].x;
          acc[rr][1] += wv[j] * ha[j].y;
          acc[rr][2] += wv[j] * ha[j].z;
          acc[rr][3] += wv[j] * ha[j].w;
          acc[rr][4] += wv[j] * hb[j].x;
          acc[rr][5] += wv[j] * hb[j].y;
          acc[rr][6] += wv[j] * hb[j].z;
          acc[rr][7] += wv[j] * hb[j].w;
        }
      }
    }
  }

  #pragma unroll
  for (int rr = 0; rr < 2; ++rr) {
    int row = rg + rr * 16;
    int g = b * NS + n0 + row;
    float inv = ws_ap[g].w;
    float* op = ws_hagg + (size_t)g * AD + c0;
    float4 o0, o1;
    o0.x = acc[rr][0] * inv; o0.y = acc[rr][1] * inv;
    o0.z = acc[rr][2] * inv; o0.w = acc[rr][3] * inv;
    o1.x = acc[rr][4] * inv; o1.y = acc[rr][5] * inv;
    o1.z = acc[rr][6] * inv; o1.w = acc[rr][7] * inv;
    *(float4*)op = o0;
    *(float4*)(op + 4) = o1;
  }
}

// ---------------- K4: MLP + gate + displacement + write pos ----------------
// grid = B*NS/16 blocks (16 rows each), 256 threads
__global__ __launch_bounds__(256) void k_mlp(
    const float* __restrict__ ws_hf, const float* __restrict__ ws_hagg,
    const float* __restrict__ W1, const float* __restrict__ b1v,
    const float* __restrict__ W2, const float* __restrict__ b2v,
    const float4* __restrict__ ws_x, const float4* __restrict__ ws_ap,
    float* __restrict__ out_pos) {
  __shared__ float z[16][260];
  __shared__ float hl[16][516];
  __shared__ float pr[16][4];

  int r0 = blockIdx.x * 16;          // global row b*NS+n
  int tid = threadIdx.x;

  for (int i = tid; i < 16 * AD; i += 256) {
    int r = i >> 7, c = i & 127;
    z[r][c]       = ws_hf  [(size_t)(r0 + r) * AD + c];
    z[r][128 + c] = ws_hagg[(size_t)(r0 + r) * AD + c];
  }
  __syncthreads();

  int jq = (tid & 127) * 4;          // hidden quad
  int rh = tid >> 7;                 // row half: rows rh*8..rh*8+7
  float h[8][4];
  #pragma unroll
  for (int r = 0; r < 8; ++r)
    #pragma unroll
    for (int j = 0; j < 4; ++j) h[r][j] = b1v[jq + j];

  for (int kq = 0; kq < 64; ++kq) {
    float4 wr[4];
    #pragma unroll
    for (int kk = 0; kk < 4; ++kk)
      wr[kk] = *(const float4*)&W1[(size_t)(kq * 4 + kk) * HID + jq];
    #pragma unroll
    for (int r = 0; r < 8; ++r) {
      float4 zq = *(const float4*)&z[rh * 8 + r][kq * 4];
      h[r][0] += zq.x * wr[0].x + zq.y * wr[1].x + zq.z * wr[2].x + zq.w * wr[3].x;
      h[r][1] += zq.x * wr[0].y + zq.y * wr[1].y + zq.z * wr[2].y + zq.w * wr[3].y;
      h[r][2] += zq.x * wr[0].z + zq.y * wr[1].z + zq.z * wr[2].z + zq.w * wr[3].z;
      h[r][3] += zq.x * wr[0].w + zq.y * wr[1].w + zq.z * wr[2].w + zq.w * wr[3].w;
    }
  }
  #pragma unroll
  for (int r = 0; r < 8; ++r)
    #pragma unroll
    for (int j = 0; j < 4; ++j)
      hl[rh * 8 + r][jq + j] = fmaxf(h[r][j], 0.f);
  __syncthreads();

  if (tid < 48) {
    int row = tid & 15, o = tid >> 4;     // o in 0..2
    float p = b2v[o];
    for (int k = 0; k < HID; ++k) p += hl[row][k] * W2[k * 3 + o];
    pr[row][o] = p;
  }
  __syncthreads();

  if (tid < 16) {
    int g = r0 + tid;
    float4 xn = ws_x[g];
    float4 apv = ws_ap[g];
    float g0 = tanhf(pr[tid][0]);
    float g1 = tanhf(pr[tid][1]);
    float g2 = tanhf(pr[tid][2]);
    float vd = xn.w;
    out_pos[(size_t)g * 3 + 0] = xn.x + apv.x * g0 * vd;
    out_pos[(size_t)g * 3 + 1] = xn.y + apv.y * g1 * vd;
    out_pos[(size_t)g * 3 + 2] = xn.z + apv.z * g2 * vd;
  }
}

extern "C" void kernel_launch(void* const* d_in, const int* in_sizes, int n_in,
                              void* d_out, int out_size, void* d_ws, size_t ws_size,
                              hipStream_t stream) {
  const float* bb    = (const float*)d_in[0];
  const float* sf    = (const float*)d_in[1];
  const float* aa    = (const float*)d_in[2];
  // d_in[3] residue_batch: unused by the reference math
  const float* mask  = (const float*)d_in[4];
  const float* pm    = (const float*)d_in[5];
  const float* emb   = (const float*)d_in[6];
  const float* W1    = (const float*)d_in[7];
  const float* b1v   = (const float*)d_in[8];
  const float* W2    = (const float*)d_in[9];
  const float* b2v   = (const float*)d_in[10];
  const float* noise = (const float*)d_in[11];

  float* out_mask = (float*)d_out;                       // B*L*37 = 11840
  float* out_pos  = (float*)d_out + BB * LL * NAT;       // B*L*34*3 = 32640

  float* ws = (float*)d_ws;
  const size_t n_x    = (size_t)BB * NS * 4;             // float4 x+valid
  const size_t n_hf   = (size_t)BB * NS * AD;
  const size_t n_ap   = (size_t)BB * NS * 4;             // float4 aggpos+inv
  float4* ws_x    = (float4*)ws;
  float*  ws_hf   = ws + n_x;
  float4* ws_ap   = (float4*)(ws + n_x + n_hf);
  float*  ws_hagg = ws + n_x + n_hf + n_ap;

  hipLaunchKernelGGL(k_prep, dim3(BB * LL), dim3(128), 0, stream,
                     bb, sf, aa, mask, pm, emb, noise, out_mask, ws_x, ws_hf);
  hipLaunchKernelGGL(k_degwx, dim3(BB * NS / 4), dim3(256), 0, stream,
                     ws_x, ws_ap);
  hipLaunchKernelGGL(k_hagg, dim3(BB * 170), dim3(256), 0, stream,
                     ws_x, ws_hf, ws_ap, ws_hagg);
  hipLaunchKernelGGL(k_mlp, dim3(BB * NS / 16), dim3(256), 0, stream,
                     ws_hf, ws_hagg, W1, b1v, W2, b2v, ws_x, ws_ap, out_pos);
}

// Round 3
// 259.259 us; speedup vs baseline: 3.0742x; 3.0742x over previous
//
#include <hip/hip_runtime.h>
#include <hip/hip_bf16.h>
#include <math.h>

#define BB 2
#define LL 160
#define NSC 34
#define NS (LL * NSC)      // 5440
#define AD 128
#define HID 512
#define NAT 37
#define PEN 1.0e9f

typedef __attribute__((ext_vector_type(4))) float f32x4;
typedef __attribute__((ext_vector_type(8))) short s16x8;

// ---------------- K1: prep ----------------
// grid = B*L blocks, 128 threads
__global__ __launch_bounds__(128) void k_prep(
    const float* __restrict__ bb, const float* __restrict__ sf,
    const float* __restrict__ aa, const float* __restrict__ mask,
    const float* __restrict__ pm, const float* __restrict__ emb,
    const float* __restrict__ noise,
    float* __restrict__ out_mask, float4* __restrict__ ws_xe,
    float* __restrict__ ws_val, float* __restrict__ ws_hf,
    __hip_bfloat16* __restrict__ ws_hfT) {
  int bl = blockIdx.x;                 // b*L + l
  int b = bl / LL, l = bl % LL;
  int tid = threadIdx.x;

  // argmax over 20 (first max wins, matches jnp.argmax)
  const float* ap = aa + bl * 20;
  float mv = ap[0]; int rt = 0;
  for (int r = 1; r < 20; ++r) { float v = ap[r]; if (v > mv) { mv = v; rt = r; } }
  float mk = mask[bl];
  const float* pmr = pm + rt * NAT;

  if (tid < NAT) out_mask[bl * NAT + tid] = pmr[tid] * mk;

  float ca0 = bb[(bl * 3 + 1) * 3 + 0] * mk;
  float ca1 = bb[(bl * 3 + 1) * 3 + 1] * mk;
  float ca2 = bb[(bl * 3 + 1) * 3 + 2] * mk;

  if (tid < NSC) {
    int s = tid;
    float am = pmr[3 + s] * mk;
    const float* npz = noise + (bl * NSC + s) * 3;
    float x = ca0 + npz[0], y = ca1 + npz[1], z = ca2 + npz[2];
    float4 xv;
    xv.x = x; xv.y = y; xv.z = z;
    xv.w = x * x + y * y + z * z + (am > 0.f ? 0.f : PEN);
    int g = b * NS + l * NSC + s;
    ws_xe[g] = xv;
    ws_val[g] = am;
  }

  float sv = sf[(size_t)bl * AD + tid];   // tid in [0,128)
  for (int s = 0; s < NSC; ++s) {
    float am = pmr[3 + s] * mk;
    float hv = (sv + emb[(3 + s) * AD + tid] * am) * am;
    size_t g = (size_t)(b * NS + l * NSC + s);
    ws_hf[g * AD + tid] = hv;
    ws_hfT[((size_t)b * AD + tid) * NS + (l * NSC + s)] = __float2bfloat16(hv);
  }
}

// ---------------- K2: deg / w@x  (wave per row) ----------------
// grid = B*NS/4 blocks, 256 threads (4 waves)
__global__ __launch_bounds__(256) void k_degwx(
    const float4* __restrict__ ws_xe, float4* __restrict__ ws_ap) {
  int w = threadIdx.x >> 6, lane = threadIdx.x & 63;
  int gid = blockIdx.x * 4 + w;        // b*NS + n
  int b = gid / NS;
  float4 xn = ws_xe[gid];
  float x2n = xn.w;
  float deg = 0.f, wx0 = 0.f, wx1 = 0.f, wx2 = 0.f;
  const float4* xb = ws_xe + b * NS;
  for (int m = lane; m < NS; m += 64) {
    float4 xm = xb[m];
    float dt = xn.x * xm.x + xn.y * xm.y + xn.z * xm.z;
    float d2 = x2n + xm.w - 2.f * dt;
    if (d2 < 64.f) {
      float wv = __expf(d2 * -0.0078125f);
      deg += wv; wx0 += wv * xm.x; wx1 += wv * xm.y; wx2 += wv * xm.z;
    }
  }
  #pragma unroll
  for (int o = 32; o; o >>= 1) {
    deg += __shfl_xor(deg, o); wx0 += __shfl_xor(wx0, o);
    wx1 += __shfl_xor(wx1, o); wx2 += __shfl_xor(wx2, o);
  }
  if (lane == 0) {
    float inv = 1.f / (deg + 1.f);
    float4 r;
    r.x = (xn.x * deg - wx0) * inv;
    r.y = (xn.y * deg - wx1) * inv;
    r.z = (xn.z * deg - wx2) * inv;
    r.w = inv;
    ws_ap[gid] = r;
  }
}

// ---------------- K3: h_agg = (w @ hf) * inv  via MFMA bf16 ----------------
// grid = B*340 blocks (16 output rows each), 256 threads = 4 waves.
// Wave w handles K-steps s = w, w+4, ... (each step = 32 m's); partials
// reduced across waves in LDS at the end.
__global__ __launch_bounds__(256, 3) void k_hagg(
    const float4* __restrict__ ws_xe, const __hip_bfloat16* __restrict__ ws_hfT,
    const float4* __restrict__ ws_ap, float* __restrict__ ws_hagg) {
  __shared__ float sred[4][16][128];   // 32 KB

  int bid = blockIdx.x;
  int b = bid / 340, rt = bid % 340;
  int n0 = rt * 16;
  int tid = threadIdx.x;
  int w = tid >> 6, lane = tid & 63;
  int ln = lane & 15;                  // row (A) / col (B) index within tile
  int g8 = (lane >> 4) * 8;            // k-group base

  const float4* xb = ws_xe + b * NS;
  const __hip_bfloat16* hb = ws_hfT + (size_t)b * AD * NS;

  float4 xn = xb[n0 + ln];
  float x2n = xn.w;

  f32x4 acc[8];
  #pragma unroll
  for (int ct = 0; ct < 8; ++ct) acc[ct] = (f32x4){0.f, 0.f, 0.f, 0.f};

  for (int s = w; s < 170; s += 4) {
    int mb = s * 32 + g8;              // this lane-group's first m
    // x of the 8 m's this lane contributes w-values for
    float4 xm[8];
    #pragma unroll
    for (int j = 0; j < 8; ++j) xm[j] = xb[mb + j];
    // B fragments: 8 contiguous bf16 along m at channel row (ct*16 + ln)
    s16x8 bf[8];
    #pragma unroll
    for (int ct = 0; ct < 8; ++ct)
      bf[ct] = *(const s16x8*)(hb + (size_t)(ct * 16 + ln) * NS + mb);
    // A fragment: w values in registers
    union { s16x8 v; __hip_bfloat16 h[8]; } af;
    #pragma unroll
    for (int j = 0; j < 8; ++j) {
      float dt = xn.x * xm[j].x + xn.y * xm[j].y + xn.z * xm[j].z;
      float d2 = x2n + xm[j].w - 2.f * dt;
      float wv = (d2 < 64.f) ? __expf(d2 * -0.0078125f) : 0.f;
      af.h[j] = __float2bfloat16(wv);
    }
    #pragma unroll
    for (int ct = 0; ct < 8; ++ct)
      acc[ct] = __builtin_amdgcn_mfma_f32_16x16x32_bf16(af.v, bf[ct], acc[ct], 0, 0, 0);
  }

  // C/D layout: col = lane&15, row = (lane>>4)*4 + reg
  #pragma unroll
  for (int ct = 0; ct < 8; ++ct)
    #pragma unroll
    for (int r = 0; r < 4; ++r)
      sred[w][(lane >> 4) * 4 + r][ct * 16 + ln] = acc[ct][r];
  __syncthreads();

  for (int i = tid; i < 16 * 128; i += 256) {
    int row = i >> 7, c = i & 127;
    float v = sred[0][row][c] + sred[1][row][c] + sred[2][row][c] + sred[3][row][c];
    int g = b * NS + n0 + row;
    ws_hagg[(size_t)g * AD + c] = v * ws_ap[g].w;
  }
}

// ---------------- K4: MLP + gate + displacement + write pos ----------------
// grid = B*NS/16 blocks (16 rows each), 256 threads
__global__ __launch_bounds__(256) void k_mlp(
    const float* __restrict__ ws_hf, const float* __restrict__ ws_hagg,
    const float* __restrict__ W1, const float* __restrict__ b1v,
    const float* __restrict__ W2, const float* __restrict__ b2v,
    const float4* __restrict__ ws_xe, const float* __restrict__ ws_val,
    const float4* __restrict__ ws_ap, float* __restrict__ out_pos) {
  __shared__ float z[16][260];
  __shared__ float hl[16][516];
  __shared__ float w2s[HID][4];
  __shared__ float pr4[16][3][4];

  int r0 = blockIdx.x * 16;          // global row b*NS+n
  int tid = threadIdx.x;

  for (int i = tid; i < 16 * AD; i += 256) {
    int r = i >> 7, c = i & 127;
    z[r][c]       = ws_hf  [(size_t)(r0 + r) * AD + c];
    z[r][128 + c] = ws_hagg[(size_t)(r0 + r) * AD + c];
  }
  for (int i = tid; i < HID * 3; i += 256) w2s[i / 3][i % 3] = W2[i];
  __syncthreads();

  int jq = (tid & 127) * 4;          // hidden quad
  int rh = tid >> 7;                 // row half: rows rh*8..rh*8+7
  float h[8][4];
  #pragma unroll
  for (int r = 0; r < 8; ++r)
    #pragma unroll
    for (int j = 0; j < 4; ++j) h[r][j] = b1v[jq + j];

  for (int kq = 0; kq < 64; ++kq) {
    float4 wr[4];
    #pragma unroll
    for (int kk = 0; kk < 4; ++kk)
      wr[kk] = *(const float4*)&W1[(size_t)(kq * 4 + kk) * HID + jq];
    #pragma unroll
    for (int r = 0; r < 8; ++r) {
      float4 zq = *(const float4*)&z[rh * 8 + r][kq * 4];
      h[r][0] += zq.x * wr[0].x + zq.y * wr[1].x + zq.z * wr[2].x + zq.w * wr[3].x;
      h[r][1] += zq.x * wr[0].y + zq.y * wr[1].y + zq.z * wr[2].y + zq.w * wr[3].y;
      h[r][2] += zq.x * wr[0].z + zq.y * wr[1].z + zq.z * wr[2].z + zq.w * wr[3].z;
      h[r][3] += zq.x * wr[0].w + zq.y * wr[1].w + zq.z * wr[2].w + zq.w * wr[3].w;
    }
  }
  #pragma unroll
  for (int r = 0; r < 8; ++r)
    #pragma unroll
    for (int j = 0; j < 4; ++j)
      hl[rh * 8 + r][jq + j] = fmaxf(h[r][j], 0.f);
  __syncthreads();

  if (tid < 192) {
    int row = tid & 15, oq = tid >> 4;   // oq in 0..11
    int o = oq % 3, q = oq / 3;          // q in 0..3
    float p = 0.f;
    #pragma unroll 4
    for (int k = q * 128; k < q * 128 + 128; ++k) p += hl[row][k] * w2s[k][o];
    pr4[row][o][q] = p;
  }
  __syncthreads();

  if (tid < 48) {
    int row = tid & 15, o = tid >> 4;    // o in 0..2
    float p = b2v[o] + pr4[row][o][0] + pr4[row][o][1] + pr4[row][o][2] + pr4[row][o][3];
    int g = r0 + row;
    float val = ws_val[g];
    float4 xnv = ws_xe[g];
    float4 apv = ws_ap[g];
    float xc = (o == 0) ? xnv.x : (o == 1) ? xnv.y : xnv.z;
    float ac = (o == 0) ? apv.x : (o == 1) ? apv.y : apv.z;
    out_pos[(size_t)g * 3 + o] = xc + ac * tanhf(p) * val;
  }
}

extern "C" void kernel_launch(void* const* d_in, const int* in_sizes, int n_in,
                              void* d_out, int out_size, void* d_ws, size_t ws_size,
                              hipStream_t stream) {
  const float* bb    = (const float*)d_in[0];
  const float* sf    = (const float*)d_in[1];
  const float* aa    = (const float*)d_in[2];
  // d_in[3] residue_batch: unused by the reference math
  const float* mask  = (const float*)d_in[4];
  const float* pm    = (const float*)d_in[5];
  const float* emb   = (const float*)d_in[6];
  const float* W1    = (const float*)d_in[7];
  const float* b1v   = (const float*)d_in[8];
  const float* W2    = (const float*)d_in[9];
  const float* b2v   = (const float*)d_in[10];
  const float* noise = (const float*)d_in[11];

  float* out_mask = (float*)d_out;                       // B*L*37 = 11840
  float* out_pos  = (float*)d_out + BB * LL * NAT;       // B*L*34*3 = 32640

  float* ws = (float*)d_ws;
  size_t off = 0;
  float4* ws_xe = (float4*)(ws + off); off += (size_t)BB * NS * 4;   // 43520
  float4* ws_ap = (float4*)(ws + off); off += (size_t)BB * NS * 4;   // 43520
  float*  ws_val = ws + off;           off += (size_t)BB * NS;       // 10880
  float*  ws_hf = ws + off;            off += (size_t)BB * NS * AD;  // 1392640
  float*  ws_hagg = ws + off;          off += (size_t)BB * NS * AD;  // 1392640
  __hip_bfloat16* ws_hfT = (__hip_bfloat16*)(ws + off);              // 1392640 bf16

  hipLaunchKernelGGL(k_prep, dim3(BB * LL), dim3(128), 0, stream,
                     bb, sf, aa, mask, pm, emb, noise, out_mask,
                     ws_xe, ws_val, ws_hf, ws_hfT);
  hipLaunchKernelGGL(k_degwx, dim3(BB * NS / 4), dim3(256), 0, stream,
                     ws_xe, ws_ap);
  hipLaunchKernelGGL(k_hagg, dim3(BB * 340), dim3(256), 0, stream,
                     ws_xe, ws_hfT, ws_ap, ws_hagg);
  hipLaunchKernelGGL(k_mlp, dim3(BB * NS / 16), dim3(256), 0, stream,
                     ws_hf, ws_hagg, W1, b1v, W2, b2v, ws_xe, ws_val, ws_ap, out_pos);
}

// Round 4
// 228.903 us; speedup vs baseline: 3.4819x; 1.1326x over previous
//
#include <hip/hip_runtime.h>
#include <hip/hip_bf16.h>
#include <math.h>

#define BB 2
#define LL 160
#define NSC 34
#define NS (LL * NSC)      // 5440
#define TOT (BB * NS)      // 10880
#define AD 128
#define ADX 144            // 128 hf channels + {1,x,y,z} + 12 zero pad rows
#define HID 512
#define NAT 37
#define PEN 1.0e9f

typedef __attribute__((ext_vector_type(4))) float f32x4;
typedef __attribute__((ext_vector_type(8))) short s16x8;

// ---------------- K1: prep ----------------
// grid = B*L blocks, 128 threads
__global__ __launch_bounds__(128) void k_prep(
    const float* __restrict__ bb, const float* __restrict__ sf,
    const float* __restrict__ aa, const float* __restrict__ mask,
    const float* __restrict__ pm, const float* __restrict__ emb,
    const float* __restrict__ noise,
    float* __restrict__ out_mask, float4* __restrict__ ws_xe,
    float* __restrict__ ws_val, float* __restrict__ ws_hf,
    __hip_bfloat16* __restrict__ ws_hfT) {
  int bl = blockIdx.x;                 // b*L + l
  int b = bl / LL, l = bl % LL;
  int tid = threadIdx.x;

  // argmax over 20 (first max wins, matches jnp.argmax)
  const float* ap = aa + bl * 20;
  float mv = ap[0]; int rt = 0;
  for (int r = 1; r < 20; ++r) { float v = ap[r]; if (v > mv) { mv = v; rt = r; } }
  float mk = mask[bl];
  const float* pmr = pm + rt * NAT;

  if (tid < NAT) out_mask[bl * NAT + tid] = pmr[tid] * mk;

  float ca0 = bb[(bl * 3 + 1) * 3 + 0] * mk;
  float ca1 = bb[(bl * 3 + 1) * 3 + 1] * mk;
  float ca2 = bb[(bl * 3 + 1) * 3 + 2] * mk;

  if (tid < NSC) {
    int s = tid;
    float am = pmr[3 + s] * mk;
    const float* npz = noise + (bl * NSC + s) * 3;
    float x = ca0 + npz[0], y = ca1 + npz[1], z = ca2 + npz[2];
    float4 xv;
    xv.x = x; xv.y = y; xv.z = z;
    xv.w = x * x + y * y + z * z + (am > 0.f ? 0.f : PEN);
    int m = l * NSC + s;
    int g = b * NS + m;
    ws_xe[g] = xv;
    ws_val[g] = am;
    // extra B-rows for the fused deg / w@x MFMA channels
    const size_t base = (size_t)b * ADX * NS;
    ws_hfT[base + (size_t)128 * NS + m] = __float2bfloat16(1.0f);
    ws_hfT[base + (size_t)129 * NS + m] = __float2bfloat16(x);
    ws_hfT[base + (size_t)130 * NS + m] = __float2bfloat16(y);
    ws_hfT[base + (size_t)131 * NS + m] = __float2bfloat16(z);
    __hip_bfloat16 zz = __float2bfloat16(0.0f);
    for (int rr = 132; rr < ADX; ++rr)
      ws_hfT[base + (size_t)rr * NS + m] = zz;
  }

  float sv = sf[(size_t)bl * AD + tid];   // tid in [0,128)
  for (int s = 0; s < NSC; ++s) {
    float am = pmr[3 + s] * mk;
    float hv = (sv + emb[(3 + s) * AD + tid] * am) * am;
    int m = l * NSC + s;
    ws_hf[(size_t)(b * NS + m) * AD + tid] = hv;
    ws_hfT[((size_t)b * ADX + tid) * NS + m] = __float2bfloat16(hv);
  }
}

// ---------------- K2: fused (w @ [hf | 1 x y z]) via MFMA bf16 ----------------
// 32 output rows per block, K split into KC chunks; 4 waves split each chunk's
// K-steps round-robin; per-wave partial accs reduced via LDS (two 16-row passes).
// Outputs: bf16 partial h_agg planes [KC][TOT][AD] + f32 deg/wx [KC][TOT][4].
template <int KC>
__global__ __launch_bounds__(256, 3) void k_hagg(
    const float4* __restrict__ ws_xe, const __hip_bfloat16* __restrict__ ws_hfT,
    __hip_bfloat16* __restrict__ haggp, float* __restrict__ dgp) {
  constexpr int CH_MAX = (170 + KC - 1) / KC;        // max K-steps per chunk
  __shared__ union {
    float4 xs[CH_MAX * 32];
    float sred[4][16][ADX];
  } u;

  int bid = blockIdx.x;
  int b = bid / (170 * KC);
  int rem = bid % (170 * KC);
  int kc = rem / 170;
  int rt = rem % 170;
  int n0 = rt * 32;
  int sb = (kc * 170) / KC, se = ((kc + 1) * 170) / KC;

  int tid = threadIdx.x;
  int w = tid >> 6, lane = tid & 63;
  int ln = lane & 15;
  int g8 = (lane >> 4) * 8;

  const float4* xb = ws_xe + b * NS;
  const __hip_bfloat16* hb = ws_hfT + (size_t)b * ADX * NS;

  // stage this chunk's x into LDS (coalesced)
  int mcnt = (se - sb) * 32;
  for (int i = tid; i < mcnt; i += 256) u.xs[i] = xb[sb * 32 + i];

  float4 xn0 = xb[n0 + ln];
  float4 xn1 = xb[n0 + 16 + ln];
  float x2n0 = xn0.w, x2n1 = xn1.w;

  f32x4 acc[2][9];
  #pragma unroll
  for (int h = 0; h < 2; ++h)
    #pragma unroll
    for (int ct = 0; ct < 9; ++ct) acc[h][ct] = (f32x4){0.f, 0.f, 0.f, 0.f};

  __syncthreads();

  auto LOADB = [&](int s, s16x8 (&bf)[9]) {
    int mb = s * 32 + g8;
    #pragma unroll
    for (int ct = 0; ct < 9; ++ct)
      bf[ct] = *(const s16x8*)(hb + (size_t)(ct * 16 + ln) * NS + mb);
  };
  auto COMP = [&](int s, s16x8 (&bf)[9]) {
    int off = (s - sb) * 32 + g8;
    float4 xm[8];
    #pragma unroll
    for (int j = 0; j < 8; ++j) xm[j] = u.xs[off + j];
    union { s16x8 v; __hip_bfloat16 h[8]; } af0, af1;
    #pragma unroll
    for (int j = 0; j < 8; ++j) {
      float dt0 = xn0.x * xm[j].x + xn0.y * xm[j].y + xn0.z * xm[j].z;
      float dt1 = xn1.x * xm[j].x + xn1.y * xm[j].y + xn1.z * xm[j].z;
      float d20 = x2n0 + xm[j].w - 2.f * dt0;
      float d21 = x2n1 + xm[j].w - 2.f * dt1;
      float w0 = (d20 < 64.f) ? __expf(d20 * -0.0078125f) : 0.f;
      float w1 = (d21 < 64.f) ? __expf(d21 * -0.0078125f) : 0.f;
      af0.h[j] = __float2bfloat16(w0);
      af1.h[j] = __float2bfloat16(w1);
    }
    #pragma unroll
    for (int ct = 0; ct < 9; ++ct) {
      acc[0][ct] = __builtin_amdgcn_mfma_f32_16x16x32_bf16(af0.v, bf[ct], acc[0][ct], 0, 0, 0);
      acc[1][ct] = __builtin_amdgcn_mfma_f32_16x16x32_bf16(af1.v, bf[ct], acc[1][ct], 0, 0, 0);
    }
  };

  // per-wave K-steps: s = sb + w, sb + w + 4, ...
  int s0 = sb + w;
  int nst = (se > s0) ? ((se - s0 + 3) >> 2) : 0;
  s16x8 bfA[9], bfB[9];
  if (nst > 0) LOADB(s0, bfA);
  int it = 0, sA = s0;
  for (; it + 2 <= nst; it += 2) {
    int sB = sA + 4;
    LOADB(sB, bfB);
    COMP(sA, bfA);
    if (it + 2 < nst) LOADB(sB + 4, bfA);
    COMP(sB, bfB);
    sA = sB + 4;
  }
  if (it < nst) COMP(sA, bfA);

  __syncthreads();   // all waves done reading u.xs

  // cross-wave reduction, two 16-row passes (reuses u.sred)
  #pragma unroll
  for (int half = 0; half < 2; ++half) {
    #pragma unroll
    for (int ct = 0; ct < 9; ++ct)
      #pragma unroll
      for (int r = 0; r < 4; ++r)
        u.sred[w][(lane >> 4) * 4 + r][ct * 16 + ln] = acc[half][ct][r];
    __syncthreads();
    for (int i = tid; i < 16 * ADX; i += 256) {
      int row = i / ADX, c = i % ADX;
      float v = u.sred[0][row][c] + u.sred[1][row][c] +
                u.sred[2][row][c] + u.sred[3][row][c];
      int g = b * NS + n0 + half * 16 + row;
      if (c < 128)
        haggp[((size_t)kc * TOT + g) * AD + c] = __float2bfloat16(v);
      else if (c < 132)
        dgp[((size_t)kc * TOT + g) * 4 + (c - 128)] = v;
    }
    __syncthreads();
  }
}

// ---------------- K3: MLP + gate + displacement + write pos ----------------
// grid = TOT/16 blocks (16 rows each), 256 threads
__global__ __launch_bounds__(256) void k_mlp(
    const float* __restrict__ ws_hf, const __hip_bfloat16* __restrict__ haggp,
    const float* __restrict__ dgp,
    const float* __restrict__ W1, const float* __restrict__ b1v,
    const float* __restrict__ W2, const float* __restrict__ b2v,
    const float4* __restrict__ ws_xe, const float* __restrict__ ws_val,
    float* __restrict__ out_pos, int KCn) {
  __shared__ float z[16][260];
  __shared__ float hl[16][516];
  __shared__ float w2s[HID][4];
  __shared__ float pr4[16][3][4];
  __shared__ float sinv[16];
  __shared__ float sagg[16][3];

  int r0 = blockIdx.x * 16;          // global row b*NS+n
  int tid = threadIdx.x;

  if (tid < 16) {
    int g = r0 + tid;
    float deg = 0.f, w0 = 0.f, w1 = 0.f, w2 = 0.f;
    for (int kc = 0; kc < KCn; ++kc) {
      const float* dp = dgp + ((size_t)kc * TOT + g) * 4;
      deg += dp[0]; w0 += dp[1]; w1 += dp[2]; w2 += dp[3];
    }
    float inv = 1.f / (deg + 1.f);
    float4 xv = ws_xe[g];
    sinv[tid] = inv;
    sagg[tid][0] = (xv.x * deg - w0) * inv;
    sagg[tid][1] = (xv.y * deg - w1) * inv;
    sagg[tid][2] = (xv.z * deg - w2) * inv;
  }
  __syncthreads();

  for (int i = tid; i < 16 * AD; i += 256) {
    int r = i >> 7, c = i & 127;
    size_t g = (size_t)(r0 + r);
    float hs = 0.f;
    for (int kc = 0; kc < KCn; ++kc)
      hs += __bfloat162float(haggp[((size_t)kc * TOT + g) * AD + c]);
    z[r][c]       = ws_hf[g * AD + c];
    z[r][128 + c] = hs * sinv[r];
  }
  for (int i = tid; i < HID * 3; i += 256) w2s[i / 3][i % 3] = W2[i];
  __syncthreads();

  int jq = (tid & 127) * 4;          // hidden quad
  int rh = tid >> 7;                 // row half: rows rh*8..rh*8+7
  float h[8][4];
  #pragma unroll
  for (int r = 0; r < 8; ++r)
    #pragma unroll
    for (int j = 0; j < 4; ++j) h[r][j] = b1v[jq + j];

  for (int kq = 0; kq < 64; ++kq) {
    float4 wr[4];
    #pragma unroll
    for (int kk = 0; kk < 4; ++kk)
      wr[kk] = *(const float4*)&W1[(size_t)(kq * 4 + kk) * HID + jq];
    #pragma unroll
    for (int r = 0; r < 8; ++r) {
      float4 zq = *(const float4*)&z[rh * 8 + r][kq * 4];
      h[r][0] += zq.x * wr[0].x + zq.y * wr[1].x + zq.z * wr[2].x + zq.w * wr[3].x;
      h[r][1] += zq.x * wr[0].y + zq.y * wr[1].y + zq.z * wr[2].y + zq.w * wr[3].y;
      h[r][2] += zq.x * wr[0].z + zq.y * wr[1].z + zq.z * wr[2].z + zq.w * wr[3].z;
      h[r][3] += zq.x * wr[0].w + zq.y * wr[1].w + zq.z * wr[2].w + zq.w * wr[3].w;
    }
  }
  #pragma unroll
  for (int r = 0; r < 8; ++r)
    #pragma unroll
    for (int j = 0; j < 4; ++j)
      hl[rh * 8 + r][jq + j] = fmaxf(h[r][j], 0.f);
  __syncthreads();

  if (tid < 192) {
    int row = tid & 15, oq = tid >> 4;   // oq in 0..11
    int o = oq % 3, q = oq / 3;          // q in 0..3
    float p = 0.f;
    #pragma unroll 4
    for (int k = q * 128; k < q * 128 + 128; ++k) p += hl[row][k] * w2s[k][o];
    pr4[row][o][q] = p;
  }
  __syncthreads();

  if (tid < 48) {
    int row = tid & 15, o = tid >> 4;    // o in 0..2
    float p = b2v[o] + pr4[row][o][0] + pr4[row][o][1] + pr4[row][o][2] + pr4[row][o][3];
    int g = r0 + row;
    float val = ws_val[g];
    float4 xnv = ws_xe[g];
    float xc = (o == 0) ? xnv.x : (o == 1) ? xnv.y : xnv.z;
    out_pos[(size_t)g * 3 + o] = xc + sagg[row][o] * tanhf(p) * val;
  }
}

extern "C" void kernel_launch(void* const* d_in, const int* in_sizes, int n_in,
                              void* d_out, int out_size, void* d_ws, size_t ws_size,
                              hipStream_t stream) {
  const float* bb    = (const float*)d_in[0];
  const float* sf    = (const float*)d_in[1];
  const float* aa    = (const float*)d_in[2];
  // d_in[3] residue_batch: unused by the reference math
  const float* mask  = (const float*)d_in[4];
  const float* pm    = (const float*)d_in[5];
  const float* emb   = (const float*)d_in[6];
  const float* W1    = (const float*)d_in[7];
  const float* b1v   = (const float*)d_in[8];
  const float* W2    = (const float*)d_in[9];
  const float* b2v   = (const float*)d_in[10];
  const float* noise = (const float*)d_in[11];

  float* out_mask = (float*)d_out;                       // B*L*37 = 11840
  float* out_pos  = (float*)d_out + BB * LL * NAT;       // B*L*34*3 = 32640

  // workspace layout (f32 first, then bf16)
  auto need = [](int kc) -> size_t {
    size_t f = (size_t)TOT * 4 + TOT + (size_t)TOT * AD + (size_t)kc * TOT * 4; // floats
    size_t h = (size_t)kc * TOT * AD + (size_t)BB * ADX * NS;                    // bf16
    return f * 4 + h * 2;
  };
  int KCn = (ws_size >= need(4)) ? 4 : 2;

  float* ws = (float*)d_ws;
  size_t off = 0;
  float4* ws_xe = (float4*)(ws + off); off += (size_t)TOT * 4;
  float*  ws_val = ws + off;           off += (size_t)TOT;
  float*  ws_hf = ws + off;            off += (size_t)TOT * AD;
  float*  ws_dgp = ws + off;           off += (size_t)KCn * TOT * 4;
  __hip_bfloat16* ws_haggp = (__hip_bfloat16*)(ws + off);
  __hip_bfloat16* ws_hfT = ws_haggp + (size_t)KCn * TOT * AD;

  hipLaunchKernelGGL(k_prep, dim3(BB * LL), dim3(128), 0, stream,
                     bb, sf, aa, mask, pm, emb, noise, out_mask,
                     ws_xe, ws_val, ws_hf, ws_hfT);
  if (KCn == 4) {
    hipLaunchKernelGGL(k_hagg<4>, dim3(BB * 170 * 4), dim3(256), 0, stream,
                       ws_xe, ws_hfT, ws_haggp, ws_dgp);
  } else {
    hipLaunchKernelGGL(k_hagg<2>, dim3(BB * 170 * 2), dim3(256), 0, stream,
                       ws_xe, ws_hfT, ws_haggp, ws_dgp);
  }
  hipLaunchKernelGGL(k_mlp, dim3(TOT / 16), dim3(256), 0, stream,
                     ws_hf, ws_haggp, ws_dgp, W1, b1v, W2, b2v,
                     ws_xe, ws_val, out_pos, KCn);
}

// Round 5
// 186.406 us; speedup vs baseline: 4.2758x; 1.2280x over previous
//
#include <hip/hip_runtime.h>
#include <hip/hip_bf16.h>
#include <math.h>

#define BB 2
#define LL 160
#define NSC 34
#define NS (LL * NSC)      // 5440
#define TOT (BB * NS)      // 10880
#define AD 128
#define ADX 144            // 128 hf channels + {1,x,y,z} + 12 zero rows
#define HID 512
#define NAT 37
#define PEN 1.0e9f

typedef __attribute__((ext_vector_type(4))) float f32x4;
typedef __attribute__((ext_vector_type(8))) short s16x8;
typedef __attribute__((address_space(1))) const unsigned int gu32;
typedef __attribute__((address_space(3))) unsigned int lu32;

// ---------------- W1 transpose -> bf16 [HID][256] ----------------
__global__ __launch_bounds__(256) void k_wprep(
    const float* __restrict__ W1, __hip_bfloat16* __restrict__ W1T) {
  __shared__ float t[64][65];
  int j0 = (blockIdx.x >> 2) * 64;
  int c0 = (blockIdx.x & 3) * 64;
  for (int i = threadIdx.x; i < 64 * 64; i += 256) {
    int jl = i & 63, cl = i >> 6;
    t[cl][jl] = W1[(size_t)(c0 + cl) * HID + j0 + jl];
  }
  __syncthreads();
  for (int i = threadIdx.x; i < 64 * 64; i += 256) {
    int cl = i & 63, jl = i >> 6;
    W1T[(size_t)(j0 + jl) * 256 + c0 + cl] = __float2bfloat16(t[cl][jl]);
  }
}

// ---------------- per-residue prep ----------------
__global__ __launch_bounds__(64) void k_prep0(
    const float* __restrict__ bb, const float* __restrict__ aa,
    const float* __restrict__ mask, const float* __restrict__ pm,
    const float* __restrict__ noise,
    float* __restrict__ out_mask, float4* __restrict__ ws_xe,
    float* __restrict__ ws_val, __hip_bfloat16* __restrict__ ws_hfT) {
  int bl = blockIdx.x;
  int b = bl / LL, l = bl % LL;
  int tid = threadIdx.x;
  const float* ap = aa + bl * 20;
  float mv = ap[0]; int rt = 0;
  for (int r = 1; r < 20; ++r) { float v = ap[r]; if (v > mv) { mv = v; rt = r; } }
  float mk = mask[bl];
  const float* pmr = pm + rt * NAT;
  if (tid < NAT) out_mask[bl * NAT + tid] = pmr[tid] * mk;

  float ca0 = bb[(bl * 3 + 1) * 3 + 0] * mk;
  float ca1 = bb[(bl * 3 + 1) * 3 + 1] * mk;
  float ca2 = bb[(bl * 3 + 1) * 3 + 2] * mk;

  if (tid < NSC) {
    float am = pmr[3 + tid] * mk;
    const float* npz = noise + (bl * NSC + tid) * 3;
    float x = ca0 + npz[0], y = ca1 + npz[1], z = ca2 + npz[2];
    float4 xv;
    xv.x = x; xv.y = y; xv.z = z;
    xv.w = x * x + y * y + z * z + (am > 0.f ? 0.f : PEN);
    int m = l * NSC + tid;
    int g = b * NS + m;
    ws_xe[g] = xv;
    ws_val[g] = am;
    __hip_bfloat16* hT = ws_hfT + (size_t)b * ADX * NS;
    hT[(size_t)128 * NS + m] = __float2bfloat16(1.0f);
    hT[(size_t)129 * NS + m] = __float2bfloat16(x);
    hT[(size_t)130 * NS + m] = __float2bfloat16(y);
    hT[(size_t)131 * NS + m] = __float2bfloat16(z);
    __hip_bfloat16 zz = __float2bfloat16(0.0f);
    for (int rr = 132; rr < ADX; ++rr) hT[(size_t)rr * NS + m] = zz;
  }
}

// ---------------- hf transpose (coalesced hfT writes) ----------------
// block = 16 residues x 32 channels; grid = 20 * 4
__global__ __launch_bounds__(256) void k_prep1(
    const float* __restrict__ sf, const float* __restrict__ aa,
    const float* __restrict__ mask, const float* __restrict__ pm,
    const float* __restrict__ emb, __hip_bfloat16* __restrict__ ws_hfT) {
  __shared__ __hip_bfloat16 tile[32][544];
  __shared__ float ssf[16][33];
  __shared__ float semb[34][32];
  __shared__ float sam[16][34];

  int rg = blockIdx.x >> 2, cg = blockIdx.x & 3;
  int res0 = rg * 16;
  int c0 = cg * 32;
  int b = res0 / LL;
  int m0 = (res0 % LL) * NSC;
  int tid = threadIdx.x;

  if (tid < 16) {
    int bl = res0 + tid;
    const float* ap = aa + bl * 20;
    float mv = ap[0]; int rt = 0;
    for (int r = 1; r < 20; ++r) { float v = ap[r]; if (v > mv) { mv = v; rt = r; } }
    float mk = mask[bl];
    const float* pmr = pm + rt * NAT + 3;
    for (int s = 0; s < NSC; ++s) sam[tid][s] = pmr[s] * mk;
  }
  for (int i = tid; i < 16 * 32; i += 256) {
    int cl = i & 31, r = i >> 5;
    ssf[r][cl] = sf[(size_t)(res0 + r) * AD + c0 + cl];
  }
  for (int i = tid; i < 34 * 32; i += 256) {
    int cl = i & 31, s = i >> 5;
    semb[s][cl] = emb[(size_t)(3 + s) * AD + c0 + cl];
  }
  __syncthreads();
  int r = tid & 15, clb = tid >> 4;
  for (int s = 0; s < NSC; ++s) {
    float am = sam[r][s];
    #pragma unroll
    for (int k = 0; k < 2; ++k) {
      int cl = clb + k * 16;
      float hv = (ssf[r][cl] + semb[s][cl] * am) * am;
      tile[cl][r * NSC + s] = __float2bfloat16(hv);
    }
  }
  __syncthreads();
  __hip_bfloat16* hT = ws_hfT + (size_t)b * ADX * NS + m0;
  for (int c = 0; c < 32; ++c)
    for (int i = tid; i < 544; i += 256)
      hT[(size_t)(c0 + c) * NS + i] = tile[c][i];
}

// ---------------- fused (w @ [hf | 1 x y z]) via MFMA bf16 ----------------
// 64 rows/block, 4 waves row-split; shared B-tile double-buffered in LDS via
// global_load_lds with slot^(row&3) XOR swizzle (both sides).
template <int KC>
__global__ __launch_bounds__(256, 4) void k_hagg(
    const float4* __restrict__ ws_xe, const __hip_bfloat16* __restrict__ ws_hfT,
    __hip_bfloat16* __restrict__ haggp, float* __restrict__ dgp) {
  constexpr int CH_MAX = (170 + KC - 1) / KC;
  __shared__ float4 xs[CH_MAX * 32];
  __shared__ alignas(16) __hip_bfloat16 sB[2][4608];   // 2 x 144 rows x 32 bf16

  int bid = blockIdx.x;
  int b = bid / (85 * KC);
  int rem = bid % (85 * KC);
  int kc = rem / 85;
  int nt = rem % 85;
  int n0 = nt * 64;
  int sb = (kc * 170) / KC, se = ((kc + 1) * 170) / KC;
  int tid = threadIdx.x, w = tid >> 6, lane = tid & 63;
  int ln = lane & 15, g8 = (lane >> 4) * 8;

  const float4* xb = ws_xe + b * NS;
  const __hip_bfloat16* hb = ws_hfT + (size_t)b * ADX * NS;

  int mcnt = (se - sb) * 32;
  for (int i = tid; i < mcnt; i += 256) xs[i] = xb[sb * 32 + i];

  float4 xn = xb[n0 + w * 16 + ln];
  float x2n = xn.w;

  f32x4 acc[9];
  #pragma unroll
  for (int ct = 0; ct < 9; ++ct) acc[ct] = (f32x4){0.f, 0.f, 0.f, 0.f};

  auto STAGE = [&](int s, int pb) {
    const char* srcb = (const char*)(hb + (size_t)s * 32);
    #pragma unroll
    for (int k = 0; k < 3; ++k) {
      int t = tid + k * 256;
      if (t < 576) {                       // wave-uniform branch
        int row = t >> 2;
        int sl = (t & 3) ^ (row & 3);      // inverse swizzle on global source
        const gu32* gp = (const gu32*)(const void*)(srcb + (size_t)row * (NS * 2) + sl * 16);
        lu32* lp = (lu32*)(void*)((char*)&sB[pb][0] + (size_t)(t & ~63) * 16);
        __builtin_amdgcn_global_load_lds(gp, lp, 16, 0, 0);
      }
    }
  };

  STAGE(sb, 0);
  __syncthreads();

  int cur = 0;
  for (int s = sb; s < se; ++s) {
    if (s + 1 < se) STAGE(s + 1, cur ^ 1);
    int off = (s - sb) * 32 + g8;
    union { s16x8 v; __hip_bfloat16 h[8]; } af;
    #pragma unroll
    for (int j = 0; j < 8; ++j) {
      float4 xm = xs[off + j];
      float dt = xn.x * xm.x + xn.y * xm.y + xn.z * xm.z;
      float d2 = x2n + xm.w - 2.f * dt;
      float wv = (d2 < 64.f) ? __expf(d2 * -0.0078125f) : 0.f;
      af.h[j] = __float2bfloat16(wv);
    }
    const char* bbase = (const char*)&sB[cur][0];
    int slot = g8 >> 3;
    #pragma unroll
    for (int ct = 0; ct < 9; ++ct) {
      int row = ct * 16 + ln;
      int boff = (row << 6) + ((slot ^ (row & 3)) << 4);   // swizzled read
      s16x8 bf = *(const s16x8*)(bbase + boff);
      acc[ct] = __builtin_amdgcn_mfma_f32_16x16x32_bf16(af.v, bf, acc[ct], 0, 0, 0);
    }
    __syncthreads();
    cur ^= 1;
  }

  int q = lane >> 4;
  int grow = b * NS + n0 + w * 16 + q * 4;
  #pragma unroll
  for (int ct = 0; ct < 8; ++ct)
    #pragma unroll
    for (int r = 0; r < 4; ++r)
      haggp[((size_t)kc * TOT + grow + r) * AD + ct * 16 + ln] = __float2bfloat16(acc[ct][r]);
  if (ln < 4)
    #pragma unroll
    for (int r = 0; r < 4; ++r)
      dgp[((size_t)kc * TOT + grow + r) * 4 + ln] = acc[8][r];
}

// ---------------- MLP via MFMA + gate + displacement ----------------
// 32 rows/block, 2 waves (16 rows each); grid = TOT/32 = 340
__global__ __launch_bounds__(128) void k_mlp(
    const __hip_bfloat16* __restrict__ ws_hfT,
    const __hip_bfloat16* __restrict__ haggp, const float* __restrict__ dgp,
    const __hip_bfloat16* __restrict__ W1T, const float* __restrict__ b1v,
    const float* __restrict__ W2, const float* __restrict__ b2v,
    const float4* __restrict__ ws_xe, const float* __restrict__ ws_val,
    float* __restrict__ out_pos, int KCn) {
  __shared__ alignas(16) __hip_bfloat16 zt[32][264];
  __shared__ float sinv[32];
  __shared__ float sagg[32][3];

  int r0 = blockIdx.x * 32;
  int b = r0 / NS;
  int m0 = r0 % NS;
  int tid = threadIdx.x, w = tid >> 6, lane = tid & 63;
  int ln = lane & 15, g8 = (lane >> 4) * 8, q = lane >> 4;

  if (tid < 32) {
    int g = r0 + tid;
    float deg = 0.f, wx = 0.f, wy = 0.f, wz = 0.f;
    for (int kc = 0; kc < KCn; ++kc) {
      float4 d = *(const float4*)&dgp[((size_t)kc * TOT + g) * 4];
      deg += d.x; wx += d.y; wy += d.z; wz += d.w;
    }
    float inv = 1.f / (deg + 1.f);
    float4 xv = ws_xe[g];
    sinv[tid] = inv;
    sagg[tid][0] = (xv.x * deg - wx) * inv;
    sagg[tid][1] = (xv.y * deg - wy) * inv;
    sagg[tid][2] = (xv.z * deg - wz) * inv;
  }
  const __hip_bfloat16* hT = ws_hfT + (size_t)b * ADX * NS + m0;
  for (int i = tid; i < 128 * 32; i += 128) {
    int c = i >> 5, ml = i & 31;
    zt[ml][c] = hT[(size_t)c * NS + ml];
  }
  __syncthreads();
  for (int i = tid; i < 32 * 128; i += 128) {
    int ml = i >> 7, c = i & 127;
    float s = 0.f;
    for (int kc = 0; kc < KCn; ++kc)
      s += __bfloat162float(haggp[((size_t)kc * TOT + r0 + ml) * AD + c]);
    zt[ml][128 + c] = __float2bfloat16(s * sinv[ml]);
  }
  __syncthreads();

  int arow = w * 16 + ln;
  s16x8 a[8];
  #pragma unroll
  for (int kq = 0; kq < 8; ++kq)
    a[kq] = *(const s16x8*)&zt[arow][kq * 32 + g8];

  float p[4][3];
  #pragma unroll
  for (int r = 0; r < 4; ++r)
    #pragma unroll
    for (int o = 0; o < 3; ++o) p[r][o] = 0.f;

  for (int jt = 0; jt < 32; ++jt) {
    int j = jt * 16 + ln;
    f32x4 acc = (f32x4){0.f, 0.f, 0.f, 0.f};
    #pragma unroll
    for (int kq = 0; kq < 8; ++kq) {
      s16x8 bw = *(const s16x8*)&W1T[(size_t)j * 256 + kq * 32 + g8];
      acc = __builtin_amdgcn_mfma_f32_16x16x32_bf16(a[kq], bw, acc, 0, 0, 0);
    }
    float bias = b1v[j];
    float w20 = W2[j * 3 + 0], w21 = W2[j * 3 + 1], w22 = W2[j * 3 + 2];
    #pragma unroll
    for (int r = 0; r < 4; ++r) {
      float h = fmaxf(acc[r] + bias, 0.f);
      p[r][0] += h * w20; p[r][1] += h * w21; p[r][2] += h * w22;
    }
  }
  #pragma unroll
  for (int r = 0; r < 4; ++r)
    #pragma unroll
    for (int o = 0; o < 3; ++o) {
      p[r][o] += __shfl_xor(p[r][o], 1);
      p[r][o] += __shfl_xor(p[r][o], 2);
      p[r][o] += __shfl_xor(p[r][o], 4);
      p[r][o] += __shfl_xor(p[r][o], 8);
    }
  if (ln == 0) {
    #pragma unroll
    for (int r = 0; r < 4; ++r) {
      int rl = w * 16 + q * 4 + r;
      int g = r0 + rl;
      float val = ws_val[g];
      float4 xv = ws_xe[g];
      float xc[3] = {xv.x, xv.y, xv.z};
      #pragma unroll
      for (int o = 0; o < 3; ++o) {
        float gate = tanhf(p[r][o] + b2v[o]);
        out_pos[(size_t)g * 3 + o] = xc[o] + sagg[rl][o] * gate * val;
      }
    }
  }
}

extern "C" void kernel_launch(void* const* d_in, const int* in_sizes, int n_in,
                              void* d_out, int out_size, void* d_ws, size_t ws_size,
                              hipStream_t stream) {
  const float* bb    = (const float*)d_in[0];
  const float* sf    = (const float*)d_in[1];
  const float* aa    = (const float*)d_in[2];
  const float* mask  = (const float*)d_in[4];
  const float* pm    = (const float*)d_in[5];
  const float* emb   = (const float*)d_in[6];
  const float* W1    = (const float*)d_in[7];
  const float* b1v   = (const float*)d_in[8];
  const float* W2    = (const float*)d_in[9];
  const float* b2v   = (const float*)d_in[10];
  const float* noise = (const float*)d_in[11];

  float* out_mask = (float*)d_out;
  float* out_pos  = (float*)d_out + BB * LL * NAT;

  auto need = [](int kc) -> size_t {
    size_t f = (size_t)TOT * 5 + (size_t)kc * TOT * 4;
    size_t h = (size_t)HID * 256 + (size_t)BB * ADX * NS + (size_t)kc * TOT * AD;
    return f * 4 + h * 2;
  };
  int KCn = (ws_size >= need(8)) ? 8 : 4;

  float* ws = (float*)d_ws;
  size_t off = 0;
  float4* ws_xe = (float4*)(ws + off); off += (size_t)TOT * 4;
  float*  ws_val = ws + off;           off += (size_t)TOT;
  float*  ws_dgp = ws + off;           off += (size_t)KCn * TOT * 4;
  __hip_bfloat16* ws_w1t  = (__hip_bfloat16*)(ws + off);
  __hip_bfloat16* ws_hfT  = ws_w1t + (size_t)HID * 256;
  __hip_bfloat16* ws_haggp = ws_hfT + (size_t)BB * ADX * NS;

  hipLaunchKernelGGL(k_wprep, dim3(32), dim3(256), 0, stream, W1, ws_w1t);
  hipLaunchKernelGGL(k_prep0, dim3(BB * LL), dim3(64), 0, stream,
                     bb, aa, mask, pm, noise, out_mask, ws_xe, ws_val, ws_hfT);
  hipLaunchKernelGGL(k_prep1, dim3((BB * LL / 16) * 4), dim3(256), 0, stream,
                     sf, aa, mask, pm, emb, ws_hfT);
  if (KCn == 8) {
    hipLaunchKernelGGL(k_hagg<8>, dim3(BB * 85 * 8), dim3(256), 0, stream,
                       ws_xe, ws_hfT, ws_haggp, ws_dgp);
  } else {
    hipLaunchKernelGGL(k_hagg<4>, dim3(BB * 85 * 4), dim3(256), 0, stream,
                       ws_xe, ws_hfT, ws_haggp, ws_dgp);
  }
  hipLaunchKernelGGL(k_mlp, dim3(TOT / 32), dim3(128), 0, stream,
                     ws_hfT, ws_haggp, ws_dgp, ws_w1t, b1v, W2, b2v,
                     ws_xe, ws_val, out_pos, KCn);
}

// Round 6
// 108.346 us; speedup vs baseline: 7.3563x; 1.7205x over previous
//
#include <hip/hip_runtime.h>
#include <hip/hip_bf16.h>
#include <math.h>

#define BB 2
#define LL 160
#define NSC 34
#define NS (LL * NSC)      // 5440
#define TOT (BB * NS)      // 10880
#define AD 128
#define ADX 144            // 128 hf channels + {1,x,y,z} + 12 zero rows
#define HID 512
#define NAT 37
#define JS 8               // j-split for k_mlp
#define PEN 1.0e9f

typedef __attribute__((ext_vector_type(4))) float f32x4;
typedef __attribute__((ext_vector_type(8))) short s16x8;
typedef __attribute__((address_space(1))) const unsigned int gu32;
typedef __attribute__((address_space(3))) unsigned int lu32;

// ---------------- W1 transpose -> bf16 [HID][256] ----------------
__global__ __launch_bounds__(256) void k_wprep(
    const float* __restrict__ W1, __hip_bfloat16* __restrict__ W1T) {
  __shared__ float t[64][65];
  int j0 = (blockIdx.x >> 2) * 64;
  int c0 = (blockIdx.x & 3) * 64;
  for (int i = threadIdx.x; i < 64 * 64; i += 256) {
    int jl = i & 63, cl = i >> 6;
    t[cl][jl] = W1[(size_t)(c0 + cl) * HID + j0 + jl];
  }
  __syncthreads();
  for (int i = threadIdx.x; i < 64 * 64; i += 256) {
    int cl = i & 63, jl = i >> 6;
    W1T[(size_t)(j0 + jl) * 256 + c0 + cl] = __float2bfloat16(t[cl][jl]);
  }
}

// ---------------- per-residue prep ----------------
__global__ __launch_bounds__(64) void k_prep0(
    const float* __restrict__ bb, const float* __restrict__ aa,
    const float* __restrict__ mask, const float* __restrict__ pm,
    const float* __restrict__ noise,
    float* __restrict__ out_mask, float4* __restrict__ ws_xe,
    float* __restrict__ ws_val, __hip_bfloat16* __restrict__ ws_hfT) {
  int bl = blockIdx.x;
  int b = bl / LL, l = bl % LL;
  int tid = threadIdx.x;
  const float* ap = aa + bl * 20;
  float mv = ap[0]; int rt = 0;
  for (int r = 1; r < 20; ++r) { float v = ap[r]; if (v > mv) { mv = v; rt = r; } }
  float mk = mask[bl];
  const float* pmr = pm + rt * NAT;
  if (tid < NAT) out_mask[bl * NAT + tid] = pmr[tid] * mk;

  float ca0 = bb[(bl * 3 + 1) * 3 + 0] * mk;
  float ca1 = bb[(bl * 3 + 1) * 3 + 1] * mk;
  float ca2 = bb[(bl * 3 + 1) * 3 + 2] * mk;

  if (tid < NSC) {
    float am = pmr[3 + tid] * mk;
    const float* npz = noise + (bl * NSC + tid) * 3;
    float x = ca0 + npz[0], y = ca1 + npz[1], z = ca2 + npz[2];
    float4 xv;
    xv.x = x; xv.y = y; xv.z = z;
    xv.w = x * x + y * y + z * z + (am > 0.f ? 0.f : PEN);
    int m = l * NSC + tid;
    int g = b * NS + m;
    ws_xe[g] = xv;
    ws_val[g] = am;
    __hip_bfloat16* hT = ws_hfT + (size_t)b * ADX * NS;
    hT[(size_t)128 * NS + m] = __float2bfloat16(1.0f);
    hT[(size_t)129 * NS + m] = __float2bfloat16(x);
    hT[(size_t)130 * NS + m] = __float2bfloat16(y);
    hT[(size_t)131 * NS + m] = __float2bfloat16(z);
    __hip_bfloat16 zz = __float2bfloat16(0.0f);
    for (int rr = 132; rr < ADX; ++rr) hT[(size_t)rr * NS + m] = zz;
  }
}

// ---------------- hf transpose + z hf-half ----------------
// block = 16 residues x 32 channels; grid = 20 * 4
__global__ __launch_bounds__(256) void k_prep1(
    const float* __restrict__ sf, const float* __restrict__ aa,
    const float* __restrict__ mask, const float* __restrict__ pm,
    const float* __restrict__ emb, __hip_bfloat16* __restrict__ ws_hfT,
    __hip_bfloat16* __restrict__ ws_z) {
  __shared__ __hip_bfloat16 tile[32][544];
  __shared__ float ssf[16][33];
  __shared__ float semb[34][32];
  __shared__ float sam[16][34];

  int rg = blockIdx.x >> 2, cg = blockIdx.x & 3;
  int res0 = rg * 16;
  int c0 = cg * 32;
  int b = res0 / LL;
  int m0 = (res0 % LL) * NSC;
  int tid = threadIdx.x;

  if (tid < 16) {
    int bl = res0 + tid;
    const float* ap = aa + bl * 20;
    float mv = ap[0]; int rt = 0;
    for (int r = 1; r < 20; ++r) { float v = ap[r]; if (v > mv) { mv = v; rt = r; } }
    float mk = mask[bl];
    const float* pmr = pm + rt * NAT + 3;
    for (int s = 0; s < NSC; ++s) sam[tid][s] = pmr[s] * mk;
  }
  for (int i = tid; i < 16 * 32; i += 256) {
    int cl = i & 31, r = i >> 5;
    ssf[r][cl] = sf[(size_t)(res0 + r) * AD + c0 + cl];
  }
  for (int i = tid; i < 34 * 32; i += 256) {
    int cl = i & 31, s = i >> 5;
    semb[s][cl] = emb[(size_t)(3 + s) * AD + c0 + cl];
  }
  __syncthreads();
  int r = tid & 15, clb = tid >> 4;
  for (int s = 0; s < NSC; ++s) {
    float am = sam[r][s];
    #pragma unroll
    for (int k = 0; k < 2; ++k) {
      int cl = clb + k * 16;
      float hv = (ssf[r][cl] + semb[s][cl] * am) * am;
      tile[cl][r * NSC + s] = __float2bfloat16(hv);
    }
  }
  __syncthreads();
  __hip_bfloat16* hT = ws_hfT + (size_t)b * ADX * NS + m0;
  for (int c = 0; c < 32; ++c)
    for (int i = tid; i < 544; i += 256)
      hT[(size_t)(c0 + c) * NS + i] = tile[c][i];
  // z hf-half, row-major
  for (int i = tid; i < 544; i += 256) {
    size_t zrow = ((size_t)b * NS + m0 + i) * 256 + c0;
    #pragma unroll
    for (int cq = 0; cq < 4; ++cq) {
      union { s16x8 v; __hip_bfloat16 h[8]; } u4;
      #pragma unroll
      for (int jj = 0; jj < 8; ++jj) u4.h[jj] = tile[cq * 8 + jj][i];
      *(s16x8*)(ws_z + zrow + cq * 8) = u4.v;
    }
  }
}

// ---------------- fused (w @ [hf | 1 x y z]) via MFMA bf16 ----------------
template <int KC>
__global__ __launch_bounds__(256, 4) void k_hagg(
    const float4* __restrict__ ws_xe, const __hip_bfloat16* __restrict__ ws_hfT,
    __hip_bfloat16* __restrict__ haggp, float* __restrict__ dgp) {
  constexpr int CH_MAX = (170 + KC - 1) / KC;
  __shared__ float4 xs[CH_MAX * 32];
  __shared__ alignas(16) __hip_bfloat16 sB[2][4608];   // 2 x 144 rows x 32 bf16

  int bid = blockIdx.x;
  int b = bid / (85 * KC);
  int rem = bid % (85 * KC);
  int kc = rem / 85;
  int nt = rem % 85;
  int n0 = nt * 64;
  int sb = (kc * 170) / KC, se = ((kc + 1) * 170) / KC;
  int tid = threadIdx.x, w = tid >> 6, lane = tid & 63;
  int ln = lane & 15, g8 = (lane >> 4) * 8;

  const float4* xb = ws_xe + b * NS;
  const __hip_bfloat16* hb = ws_hfT + (size_t)b * ADX * NS;

  int mcnt = (se - sb) * 32;
  for (int i = tid; i < mcnt; i += 256) xs[i] = xb[sb * 32 + i];

  float4 xn = xb[n0 + w * 16 + ln];
  float x2n = xn.w;

  f32x4 acc[9];
  #pragma unroll
  for (int ct = 0; ct < 9; ++ct) acc[ct] = (f32x4){0.f, 0.f, 0.f, 0.f};

  auto STAGE = [&](int s, int pb) {
    const char* srcb = (const char*)(hb + (size_t)s * 32);
    #pragma unroll
    for (int k = 0; k < 3; ++k) {
      int t = tid + k * 256;
      if (t < 576) {
        int row = t >> 2;
        int sl = (t & 3) ^ (row & 3);
        const gu32* gp = (const gu32*)(const void*)(srcb + (size_t)row * (NS * 2) + sl * 16);
        lu32* lp = (lu32*)(void*)((char*)&sB[pb][0] + (size_t)(t & ~63) * 16);
        __builtin_amdgcn_global_load_lds(gp, lp, 16, 0, 0);
      }
    }
  };

  STAGE(sb, 0);
  __syncthreads();

  int cur = 0;
  for (int s = sb; s < se; ++s) {
    if (s + 1 < se) STAGE(s + 1, cur ^ 1);
    int off = (s - sb) * 32 + g8;
    union { s16x8 v; __hip_bfloat16 h[8]; } af;
    #pragma unroll
    for (int j = 0; j < 8; ++j) {
      float4 xm = xs[off + j];
      float dt = xn.x * xm.x + xn.y * xm.y + xn.z * xm.z;
      float d2 = x2n + xm.w - 2.f * dt;
      float wv = (d2 < 64.f) ? __expf(d2 * -0.0078125f) : 0.f;
      af.h[j] = __float2bfloat16(wv);
    }
    const char* bbase = (const char*)&sB[cur][0];
    int slot = g8 >> 3;
    #pragma unroll
    for (int ct = 0; ct < 9; ++ct) {
      int row = ct * 16 + ln;
      int boff = (row << 6) + ((slot ^ (row & 3)) << 4);
      s16x8 bf = *(const s16x8*)(bbase + boff);
      acc[ct] = __builtin_amdgcn_mfma_f32_16x16x32_bf16(af.v, bf, acc[ct], 0, 0, 0);
    }
    __syncthreads();
    cur ^= 1;
  }

  int q = lane >> 4;
  int grow = b * NS + n0 + w * 16 + q * 4;
  #pragma unroll
  for (int ct = 0; ct < 8; ++ct)
    #pragma unroll
    for (int r = 0; r < 4; ++r)
      haggp[((size_t)kc * TOT + grow + r) * AD + ct * 16 + ln] = __float2bfloat16(acc[ct][r]);
  if (ln < 4)
    #pragma unroll
    for (int r = 0; r < 4; ++r)
      dgp[((size_t)kc * TOT + grow + r) * 4 + ln] = acc[8][r];
}

// ---------------- reduce partials -> z hagg-half + ws_ai ----------------
// 16 rows/block, 256 threads: thread = row*16 + c8
__global__ __launch_bounds__(256) void k_reduce(
    const __hip_bfloat16* __restrict__ haggp, const float* __restrict__ dgp,
    const float4* __restrict__ ws_xe, float4* __restrict__ ws_ai,
    __hip_bfloat16* __restrict__ ws_z, int KCn) {
  __shared__ float sinv[16];
  int r0 = blockIdx.x * 16;
  int tid = threadIdx.x;
  if (tid < 16) {
    int g = r0 + tid;
    float deg = 0.f, wx = 0.f, wy = 0.f, wz = 0.f;
    for (int kc = 0; kc < KCn; ++kc) {
      float4 d = *(const float4*)&dgp[((size_t)kc * TOT + g) * 4];
      deg += d.x; wx += d.y; wy += d.z; wz += d.w;
    }
    float inv = 1.f / (deg + 1.f);
    float4 xv = ws_xe[g];
    float4 ai;
    ai.x = (xv.x * deg - wx) * inv;
    ai.y = (xv.y * deg - wy) * inv;
    ai.z = (xv.z * deg - wz) * inv;
    ai.w = inv;
    ws_ai[g] = ai;
    sinv[tid] = inv;
  }
  __syncthreads();
  int row = tid >> 4, c8 = tid & 15;
  int g = r0 + row;
  float s[8];
  #pragma unroll
  for (int j = 0; j < 8; ++j) s[j] = 0.f;
  for (int kc = 0; kc < KCn; ++kc) {
    union { s16x8 v; __hip_bfloat16 h[8]; } u;
    u.v = *(const s16x8*)(haggp + ((size_t)kc * TOT + g) * AD + c8 * 8);
    #pragma unroll
    for (int j = 0; j < 8; ++j) s[j] += __bfloat162float(u.h[j]);
  }
  float inv = sinv[row];
  union { s16x8 v; __hip_bfloat16 h[8]; } o;
  #pragma unroll
  for (int j = 0; j < 8; ++j) o.h[j] = __float2bfloat16(s[j] * inv);
  *(s16x8*)(ws_z + (size_t)g * 256 + 128 + c8 * 8) = o.v;
}

// ---------------- MLP layer1+2 partial via MFMA ----------------
// grid = 340 * JS, block = 128 (2 waves, 16 rows each); block does 64 hidden
__global__ __launch_bounds__(128) void k_mlp(
    const __hip_bfloat16* __restrict__ ws_z,
    const __hip_bfloat16* __restrict__ W1T, const float* __restrict__ b1v,
    const float* __restrict__ W2, float* __restrict__ pp) {
  int bid = blockIdx.x;
  int rt = bid >> 3;          // row tile (JS inner for L2 reuse of z rows)
  int js = bid & (JS - 1);
  int r0 = rt * 32;
  int tid = threadIdx.x, w = tid >> 6, lane = tid & 63;
  int ln = lane & 15, g8 = (lane >> 4) * 8, q = lane >> 4;

  int arow = r0 + w * 16 + ln;
  s16x8 a[8];
  #pragma unroll
  for (int kq = 0; kq < 8; ++kq)
    a[kq] = *(const s16x8*)(ws_z + (size_t)arow * 256 + kq * 32 + g8);

  float p[4][3];
  #pragma unroll
  for (int r = 0; r < 4; ++r)
    #pragma unroll
    for (int o = 0; o < 3; ++o) p[r][o] = 0.f;

  #pragma unroll
  for (int jt = 0; jt < HID / (JS * 16); ++jt) {
    int j = js * (HID / JS) + jt * 16 + ln;
    f32x4 acc = (f32x4){0.f, 0.f, 0.f, 0.f};
    #pragma unroll
    for (int kq = 0; kq < 8; ++kq) {
      s16x8 bw = *(const s16x8*)(W1T + (size_t)j * 256 + kq * 32 + g8);
      acc = __builtin_amdgcn_mfma_f32_16x16x32_bf16(a[kq], bw, acc, 0, 0, 0);
    }
    float bias = b1v[j];
    float w20 = W2[j * 3 + 0], w21 = W2[j * 3 + 1], w22 = W2[j * 3 + 2];
    #pragma unroll
    for (int r = 0; r < 4; ++r) {
      float h = fmaxf(acc[r] + bias, 0.f);
      p[r][0] += h * w20; p[r][1] += h * w21; p[r][2] += h * w22;
    }
  }
  #pragma unroll
  for (int r = 0; r < 4; ++r)
    #pragma unroll
    for (int o = 0; o < 3; ++o) {
      p[r][o] += __shfl_xor(p[r][o], 1);
      p[r][o] += __shfl_xor(p[r][o], 2);
      p[r][o] += __shfl_xor(p[r][o], 4);
      p[r][o] += __shfl_xor(p[r][o], 8);
    }
  if (ln == 0) {
    #pragma unroll
    for (int r = 0; r < 4; ++r) {
      int g = r0 + w * 16 + q * 4 + r;
      #pragma unroll
      for (int o = 0; o < 3; ++o)
        pp[((size_t)js * TOT + g) * 3 + o] = p[r][o];
    }
  }
}

// ---------------- final: sum partials + gate + displacement ----------------
__global__ __launch_bounds__(256) void k_fin(
    const float* __restrict__ pp, const float* __restrict__ b2v,
    const float4* __restrict__ ws_xe, const float4* __restrict__ ws_ai,
    const float* __restrict__ ws_val, float* __restrict__ out_pos) {
  int g = blockIdx.x * 256 + threadIdx.x;
  if (g >= TOT) return;
  float p0 = b2v[0], p1 = b2v[1], p2 = b2v[2];
  for (int js = 0; js < JS; ++js) {
    const float* pj = pp + ((size_t)js * TOT + g) * 3;
    p0 += pj[0]; p1 += pj[1]; p2 += pj[2];
  }
  float val = ws_val[g];
  float4 xv = ws_xe[g];
  float4 ai = ws_ai[g];
  out_pos[(size_t)g * 3 + 0] = xv.x + ai.x * tanhf(p0) * val;
  out_pos[(size_t)g * 3 + 1] = xv.y + ai.y * tanhf(p1) * val;
  out_pos[(size_t)g * 3 + 2] = xv.z + ai.z * tanhf(p2) * val;
}

extern "C" void kernel_launch(void* const* d_in, const int* in_sizes, int n_in,
                              void* d_out, int out_size, void* d_ws, size_t ws_size,
                              hipStream_t stream) {
  const float* bb    = (const float*)d_in[0];
  const float* sf    = (const float*)d_in[1];
  const float* aa    = (const float*)d_in[2];
  const float* mask  = (const float*)d_in[4];
  const float* pm    = (const float*)d_in[5];
  const float* emb   = (const float*)d_in[6];
  const float* W1    = (const float*)d_in[7];
  const float* b1v   = (const float*)d_in[8];
  const float* W2    = (const float*)d_in[9];
  const float* b2v   = (const float*)d_in[10];
  const float* noise = (const float*)d_in[11];

  float* out_mask = (float*)d_out;
  float* out_pos  = (float*)d_out + BB * LL * NAT;

  auto need = [](int kc) -> size_t {
    size_t f = (size_t)TOT * 4 + TOT + (size_t)kc * TOT * 4 +
               (size_t)TOT * 4 + (size_t)JS * TOT * 3;
    size_t h = (size_t)HID * 256 + (size_t)BB * ADX * NS +
               (size_t)kc * TOT * AD + (size_t)TOT * 256;
    return f * 4 + h * 2;
  };
  int KCn = (ws_size >= need(8)) ? 8 : ((ws_size >= need(4)) ? 4 : 2);

  float* ws = (float*)d_ws;
  size_t off = 0;
  float4* ws_xe = (float4*)(ws + off); off += (size_t)TOT * 4;
  float*  ws_val = ws + off;           off += (size_t)TOT;
  float*  ws_dgp = ws + off;           off += (size_t)KCn * TOT * 4;
  float4* ws_ai  = (float4*)(ws + off); off += (size_t)TOT * 4;
  float*  ws_pp  = ws + off;           off += (size_t)JS * TOT * 3;
  __hip_bfloat16* ws_w1t  = (__hip_bfloat16*)(ws + off);
  __hip_bfloat16* ws_hfT  = ws_w1t + (size_t)HID * 256;
  __hip_bfloat16* ws_haggp = ws_hfT + (size_t)BB * ADX * NS;
  __hip_bfloat16* ws_z = ws_haggp + (size_t)KCn * TOT * AD;

  hipLaunchKernelGGL(k_wprep, dim3(32), dim3(256), 0, stream, W1, ws_w1t);
  hipLaunchKernelGGL(k_prep0, dim3(BB * LL), dim3(64), 0, stream,
                     bb, aa, mask, pm, noise, out_mask, ws_xe, ws_val, ws_hfT);
  hipLaunchKernelGGL(k_prep1, dim3((BB * LL / 16) * 4), dim3(256), 0, stream,
                     sf, aa, mask, pm, emb, ws_hfT, ws_z);
  if (KCn == 8) {
    hipLaunchKernelGGL(k_hagg<8>, dim3(BB * 85 * 8), dim3(256), 0, stream,
                       ws_xe, ws_hfT, ws_haggp, ws_dgp);
  } else if (KCn == 4) {
    hipLaunchKernelGGL(k_hagg<4>, dim3(BB * 85 * 4), dim3(256), 0, stream,
                       ws_xe, ws_hfT, ws_haggp, ws_dgp);
  } else {
    hipLaunchKernelGGL(k_hagg<2>, dim3(BB * 85 * 2), dim3(256), 0, stream,
                       ws_xe, ws_hfT, ws_haggp, ws_dgp);
  }
  hipLaunchKernelGGL(k_reduce, dim3(TOT / 16), dim3(256), 0, stream,
                     ws_haggp, ws_dgp, ws_xe, ws_ai, ws_z, KCn);
  hipLaunchKernelGGL(k_mlp, dim3((TOT / 32) * JS), dim3(128), 0, stream,
                     ws_z, ws_w1t, b1v, W2, ws_pp);
  hipLaunchKernelGGL(k_fin, dim3((TOT + 255) / 256), dim3(256), 0, stream,
                     ws_pp, b2v, ws_xe, ws_ai, ws_val, out_pos);
}

// Round 8
// 65.355 us; speedup vs baseline: 12.1954x; 1.6578x over previous
//
#include <hip/hip_runtime.h>
#include <hip/hip_bf16.h>
#include <math.h>

#define BB 2
#define LL 160
#define NSC 34
#define NS (LL * NSC)      // 5440
#define TOT (BB * NS)      // 10880
#define AD 128
#define ADX 144            // 128 hf channels + {1,x,y,z} + 12 zero rows
#define HID 512
#define NAT 37
#define JS 8               // j-split for k_mlp
#define KC 4               // K-chunk split for k_haggc
#define NVP 1792           // max valid atoms per batch (160 x 11 = 1760, pad to 28*64)
#define NVT 28             // NVP / 64 tiles
#define NVPT (BB * NVP)    // 3584
#define PEN 1.0e9f

typedef __attribute__((ext_vector_type(4))) float f32x4;
typedef __attribute__((ext_vector_type(8))) short s16x8;
typedef __attribute__((address_space(1))) const unsigned int gu32;
typedef __attribute__((address_space(3))) unsigned int lu32;

// ---------------- W1 transpose -> bf16 [HID][256] ----------------
__global__ __launch_bounds__(256) void k_wprep(
    const float* __restrict__ W1, __hip_bfloat16* __restrict__ W1T) {
  __shared__ float t[64][65];
  int j0 = (blockIdx.x >> 2) * 64;
  int c0 = (blockIdx.x & 3) * 64;
  for (int i = threadIdx.x; i < 64 * 64; i += 256) {
    int jl = i & 63, cl = i >> 6;
    t[cl][jl] = W1[(size_t)(c0 + cl) * HID + j0 + jl];
  }
  __syncthreads();
  for (int i = threadIdx.x; i < 64 * 64; i += 256) {
    int cl = i & 63, jl = i >> 6;
    W1T[(size_t)(j0 + jl) * 256 + c0 + cl] = __float2bfloat16(t[cl][jl]);
  }
}

// ---------------- per-residue prep ----------------
__global__ __launch_bounds__(64) void k_prep0(
    const float* __restrict__ bb, const float* __restrict__ aa,
    const float* __restrict__ mask, const float* __restrict__ pm,
    const float* __restrict__ noise,
    float* __restrict__ out_mask, float4* __restrict__ ws_xe,
    float* __restrict__ ws_val) {
  int bl = blockIdx.x;
  int b = bl / LL, l = bl % LL;
  int tid = threadIdx.x;
  const float* ap = aa + bl * 20;
  float mv = ap[0]; int rt = 0;
  for (int r = 1; r < 20; ++r) { float v = ap[r]; if (v > mv) { mv = v; rt = r; } }
  float mk = mask[bl];
  const float* pmr = pm + rt * NAT;
  if (tid < NAT) out_mask[bl * NAT + tid] = pmr[tid] * mk;

  float ca0 = bb[(bl * 3 + 1) * 3 + 0] * mk;
  float ca1 = bb[(bl * 3 + 1) * 3 + 1] * mk;
  float ca2 = bb[(bl * 3 + 1) * 3 + 2] * mk;

  if (tid < NSC) {
    float am = pmr[3 + tid] * mk;   // includes atom-3 backbone slot (s=0)
    const float* npz = noise + (bl * NSC + tid) * 3;
    float x = ca0 + npz[0], y = ca1 + npz[1], z = ca2 + npz[2];
    float4 xv;
    xv.x = x; xv.y = y; xv.z = z;
    xv.w = x * x + y * y + z * z + (am > 0.f ? 0.f : PEN);
    int g = b * NS + l * NSC + tid;
    ws_xe[g] = xv;
    ws_val[g] = am;
  }
}

// ---------------- scan + compaction maps + compacted x ----------------
// grid = BB, 256 threads; validity taken directly from ws_val (robust)
__global__ __launch_bounds__(256) void k_scan(
    const float* __restrict__ ws_val, const float4* __restrict__ ws_xe,
    int* __restrict__ g2cg, int* __restrict__ cg2g, float4* __restrict__ xc) {
  __shared__ int scnt[LL];
  __shared__ int soff[LL];
  __shared__ int smap[NVP];
  int b = blockIdx.x;
  int tid = threadIdx.x;
  for (int l = tid; l < LL; l += 256) {
    int c = 0;
    for (int s = 0; s < NSC; ++s)
      if (ws_val[b * NS + l * NSC + s] > 0.f) ++c;
    scnt[l] = c;
  }
  __syncthreads();
  if (tid == 0) {
    int run = 0;
    for (int l = 0; l < LL; ++l) { soff[l] = run; run += scnt[l]; }
  }
  __syncthreads();
  for (int j = tid; j < NVP; j += 256) smap[j] = -1;
  __syncthreads();
  for (int l = tid; l < LL; l += 256) {
    int o = soff[l], k = 0;
    for (int s = 0; s < NSC; ++s) {
      int m = l * NSC + s;
      if (ws_val[b * NS + m] > 0.f) {
        smap[o + k] = m;
        g2cg[b * NS + m] = o + k;
        ++k;
      } else {
        g2cg[b * NS + m] = -1;
      }
    }
  }
  __syncthreads();
  for (int j = tid; j < NVP; j += 256) {
    int m = smap[j];
    cg2g[b * NVP + j] = m;
    float4 v;
    if (m >= 0) v = ws_xe[b * NS + m];
    else { v.x = 0.f; v.y = 0.f; v.z = 0.f; v.w = PEN; }
    xc[b * NVP + j] = v;
  }
}

// ---------------- compacted hf^T [b][ADX][NVP] + z hf-half ----------------
// grid = BB*NVT (64 compacted slots each), 256 threads
__global__ __launch_bounds__(256) void k_prep1c(
    const float* __restrict__ sf, const float* __restrict__ emb,
    const float* __restrict__ ws_val, const int* __restrict__ cg2g,
    const float4* __restrict__ xc, __hip_bfloat16* __restrict__ hfTc,
    __hip_bfloat16* __restrict__ ws_z) {
  __shared__ __hip_bfloat16 tile[ADX][64];
  __shared__ int sm[64];
  int bid = blockIdx.x;
  int b = bid / NVT;
  int j0 = (bid % NVT) * 64;
  int tid = threadIdx.x;
  if (tid < 64) sm[tid] = cg2g[b * NVP + j0 + tid];
  __syncthreads();

  int jl = tid >> 2, cq = tid & 3;
  int m = sm[jl];
  union { s16x8 v[4]; __hip_bfloat16 h[32]; } o;
  if (m >= 0) {
    int l = m / NSC, s = m - l * NSC;
    float am = ws_val[b * NS + m];
    const float* sfp = sf + (size_t)(b * LL + l) * AD + cq * 32;
    const float* emp = emb + (size_t)(3 + s) * AD + cq * 32;
    #pragma unroll 8
    for (int k = 0; k < 32; ++k) {
      float hv = (sfp[k] + emp[k] * am) * am;
      o.h[k] = __float2bfloat16(hv);
      tile[cq * 32 + k][jl] = o.h[k];
    }
  } else {
    __hip_bfloat16 zz = __float2bfloat16(0.0f);
    #pragma unroll 8
    for (int k = 0; k < 32; ++k) { o.h[k] = zz; tile[cq * 32 + k][jl] = zz; }
  }
  // z hf-half row-major
  {
    __hip_bfloat16* zp = ws_z + ((size_t)(b * NVP + j0 + jl)) * 256 + cq * 32;
    #pragma unroll
    for (int q = 0; q < 4; ++q) *(s16x8*)(zp + q * 8) = o.v[q];
  }
  if (cq == 0) {
    float4 xj = xc[b * NVP + j0 + jl];
    tile[128][jl] = __float2bfloat16(m >= 0 ? 1.0f : 0.0f);
    tile[129][jl] = __float2bfloat16(xj.x);
    tile[130][jl] = __float2bfloat16(xj.y);
    tile[131][jl] = __float2bfloat16(xj.z);
    __hip_bfloat16 zz = __float2bfloat16(0.0f);
    for (int rr = 132; rr < ADX; ++rr) tile[rr][jl] = zz;
  }
  __syncthreads();
  // stream out: 144 rows x 64 cols
  for (int i = tid; i < ADX * 2; i += 256) {
    int r = i >> 1, hf = i & 1;
    __hip_bfloat16* dst = hfTc + (size_t)b * ADX * NVP + (size_t)r * NVP + j0 + hf * 32;
    const __hip_bfloat16* srow = &tile[r][hf * 32];
    #pragma unroll
    for (int q = 0; q < 4; ++q)
      *(s16x8*)(dst + q * 8) = *(const s16x8*)(srow + q * 8);
  }
}

// ---------------- compacted (w @ [hf | 1 x y z]) via MFMA bf16 ----------------
// grid = BB * NVT * KC, 256 threads; 64 rows/block, 4 waves row-split
__global__ __launch_bounds__(256, 4) void k_haggc(
    const float4* __restrict__ xc, const __hip_bfloat16* __restrict__ hfTc,
    __hip_bfloat16* __restrict__ haggp, float* __restrict__ dgp) {
  constexpr int NSTEP = NVP / 32;                    // 56
  constexpr int CH_MAX = (NSTEP + KC - 1) / KC;      // 14
  __shared__ float4 xs[(CH_MAX * 4 + 1) * 9];        // padded: group stride 9
  __shared__ alignas(16) __hip_bfloat16 sB[2][4608]; // 2 x 144 rows x 32 bf16

  int bid = blockIdx.x;
  int b = bid / (NVT * KC);
  int rem = bid % (NVT * KC);
  int kc = rem / NVT;
  int nt = rem % NVT;
  int n0 = nt * 64;
  int sb = (kc * NSTEP) / KC, se = ((kc + 1) * NSTEP) / KC;
  int tid = threadIdx.x, w = tid >> 6, lane = tid & 63;
  int ln = lane & 15, g8 = (lane >> 4) * 8;

  const float4* xb = xc + b * NVP;
  const __hip_bfloat16* hb = hfTc + (size_t)b * ADX * NVP;

  int mcnt = (se - sb) * 32;
  for (int i = tid; i < mcnt; i += 256)
    xs[(i >> 3) * 9 + (i & 7)] = xb[sb * 32 + i];

  float4 xn = xb[n0 + w * 16 + ln];
  float x2n = xn.w;

  f32x4 acc[9];
  #pragma unroll
  for (int ct = 0; ct < 9; ++ct) acc[ct] = (f32x4){0.f, 0.f, 0.f, 0.f};

  auto STAGE = [&](int s, int pb) {
    const char* srcb = (const char*)(hb + (size_t)s * 32);
    #pragma unroll
    for (int k = 0; k < 3; ++k) {
      int t = tid + k * 256;
      if (t < 576) {
        int row = t >> 2;
        int sl = (t & 3) ^ (row & 3);
        const gu32* gp = (const gu32*)(const void*)(srcb + (size_t)row * (NVP * 2) + sl * 16);
        lu32* lp = (lu32*)(void*)((char*)&sB[pb][0] + (size_t)(t & ~63) * 16);
        __builtin_amdgcn_global_load_lds(gp, lp, 16, 0, 0);
      }
    }
  };

  STAGE(sb, 0);
  __syncthreads();

  int cur = 0;
  for (int s = sb; s < se; ++s) {
    if (s + 1 < se) STAGE(s + 1, cur ^ 1);
    int grp = (s - sb) * 4 + (g8 >> 3);
    union { s16x8 v; __hip_bfloat16 h[8]; } af;
    #pragma unroll
    for (int j = 0; j < 8; ++j) {
      float4 xm = xs[grp * 9 + j];
      float dt = xn.x * xm.x + xn.y * xm.y + xn.z * xm.z;
      float d2 = x2n + xm.w - 2.f * dt;
      float wv = (d2 < 64.f) ? __expf(d2 * -0.0078125f) : 0.f;
      af.h[j] = __float2bfloat16(wv);
    }
    const char* bbase = (const char*)&sB[cur][0];
    int slot = g8 >> 3;
    #pragma unroll
    for (int ct = 0; ct < 9; ++ct) {
      int row = ct * 16 + ln;
      int boff = (row << 6) + ((slot ^ (row & 3)) << 4);
      s16x8 bf = *(const s16x8*)(bbase + boff);
      acc[ct] = __builtin_amdgcn_mfma_f32_16x16x32_bf16(af.v, bf, acc[ct], 0, 0, 0);
    }
    __syncthreads();
    cur ^= 1;
  }

  int q = lane >> 4;
  int grow = b * NVP + n0 + w * 16 + q * 4;
  #pragma unroll
  for (int ct = 0; ct < 8; ++ct)
    #pragma unroll
    for (int r = 0; r < 4; ++r)
      haggp[((size_t)kc * NVPT + grow + r) * AD + ct * 16 + ln] = __float2bfloat16(acc[ct][r]);
  if (ln < 4)
    #pragma unroll
    for (int r = 0; r < 4; ++r)
      dgp[((size_t)kc * NVPT + grow + r) * 4 + ln] = acc[8][r];
}

// ---------------- reduce partials -> z hagg-half + ws_ai ----------------
// grid = NVPT/16, 256 threads
__global__ __launch_bounds__(256) void k_reduce(
    const __hip_bfloat16* __restrict__ haggp, const float* __restrict__ dgp,
    const float4* __restrict__ xc, float4* __restrict__ ws_ai,
    __hip_bfloat16* __restrict__ ws_z) {
  __shared__ float sinv[16];
  int r0 = blockIdx.x * 16;
  int tid = threadIdx.x;
  if (tid < 16) {
    int g = r0 + tid;
    float deg = 0.f, wx = 0.f, wy = 0.f, wz = 0.f;
    #pragma unroll
    for (int kc = 0; kc < KC; ++kc) {
      float4 d = *(const float4*)&dgp[((size_t)kc * NVPT + g) * 4];
      deg += d.x; wx += d.y; wy += d.z; wz += d.w;
    }
    float inv = 1.f / (deg + 1.f);
    float4 xv = xc[g];
    float4 ai;
    ai.x = (xv.x * deg - wx) * inv;
    ai.y = (xv.y * deg - wy) * inv;
    ai.z = (xv.z * deg - wz) * inv;
    ai.w = inv;
    ws_ai[g] = ai;
    sinv[tid] = inv;
  }
  __syncthreads();
  int row = tid >> 4, c8 = tid & 15;
  int g = r0 + row;
  float s[8];
  #pragma unroll
  for (int j = 0; j < 8; ++j) s[j] = 0.f;
  #pragma unroll
  for (int kc = 0; kc < KC; ++kc) {
    union { s16x8 v; __hip_bfloat16 h[8]; } u;
    u.v = *(const s16x8*)(haggp + ((size_t)kc * NVPT + g) * AD + c8 * 8);
    #pragma unroll
    for (int j = 0; j < 8; ++j) s[j] += __bfloat162float(u.h[j]);
  }
  float inv = sinv[row];
  union { s16x8 v; __hip_bfloat16 h[8]; } o;
  #pragma unroll
  for (int j = 0; j < 8; ++j) o.h[j] = __float2bfloat16(s[j] * inv);
  *(s16x8*)(ws_z + (size_t)g * 256 + 128 + c8 * 8) = o.v;
}

// ---------------- MLP layer1+2 partial via MFMA ----------------
// grid = (NVPT/32) * JS, block = 128 (2 waves, 16 rows each)
__global__ __launch_bounds__(128) void k_mlp(
    const __hip_bfloat16* __restrict__ ws_z,
    const __hip_bfloat16* __restrict__ W1T, const float* __restrict__ b1v,
    const float* __restrict__ W2, float* __restrict__ pp) {
  int bid = blockIdx.x;
  int rt = bid >> 3;
  int js = bid & (JS - 1);
  int r0 = rt * 32;
  int tid = threadIdx.x, w = tid >> 6, lane = tid & 63;
  int ln = lane & 15, g8 = (lane >> 4) * 8, q = lane >> 4;

  int arow = r0 + w * 16 + ln;
  s16x8 a[8];
  #pragma unroll
  for (int kq = 0; kq < 8; ++kq)
    a[kq] = *(const s16x8*)(ws_z + (size_t)arow * 256 + kq * 32 + g8);

  float p[4][3];
  #pragma unroll
  for (int r = 0; r < 4; ++r)
    #pragma unroll
    for (int o = 0; o < 3; ++o) p[r][o] = 0.f;

  #pragma unroll
  for (int jt = 0; jt < HID / (JS * 16); ++jt) {
    int j = js * (HID / JS) + jt * 16 + ln;
    f32x4 acc = (f32x4){0.f, 0.f, 0.f, 0.f};
    #pragma unroll
    for (int kq = 0; kq < 8; ++kq) {
      s16x8 bw = *(const s16x8*)(W1T + (size_t)j * 256 + kq * 32 + g8);
      acc = __builtin_amdgcn_mfma_f32_16x16x32_bf16(a[kq], bw, acc, 0, 0, 0);
    }
    float bias = b1v[j];
    float w20 = W2[j * 3 + 0], w21 = W2[j * 3 + 1], w22 = W2[j * 3 + 2];
    #pragma unroll
    for (int r = 0; r < 4; ++r) {
      float h = fmaxf(acc[r] + bias, 0.f);
      p[r][0] += h * w20; p[r][1] += h * w21; p[r][2] += h * w22;
    }
  }
  #pragma unroll
  for (int r = 0; r < 4; ++r)
    #pragma unroll
    for (int o = 0; o < 3; ++o) {
      p[r][o] += __shfl_xor(p[r][o], 1);
      p[r][o] += __shfl_xor(p[r][o], 2);
      p[r][o] += __shfl_xor(p[r][o], 4);
      p[r][o] += __shfl_xor(p[r][o], 8);
    }
  if (ln == 0) {
    #pragma unroll
    for (int r = 0; r < 4; ++r) {
      int g = r0 + w * 16 + q * 4 + r;
      #pragma unroll
      for (int o = 0; o < 3; ++o)
        pp[((size_t)js * NVPT + g) * 3 + o] = p[r][o];
    }
  }
}

// ---------------- final: scatter back to all atoms ----------------
__global__ __launch_bounds__(256) void k_fin(
    const float* __restrict__ pp, const float* __restrict__ b2v,
    const float4* __restrict__ ws_xe, const float* __restrict__ ws_val,
    const float4* __restrict__ ws_ai, const int* __restrict__ g2cg,
    float* __restrict__ out_pos) {
  int g = blockIdx.x * 256 + threadIdx.x;
  if (g >= TOT) return;
  int b = g / NS;
  float4 xv = ws_xe[g];
  int j = g2cg[g];
  float o0 = xv.x, o1 = xv.y, o2 = xv.z;
  if (j >= 0) {
    int cg = b * NVP + j;
    float p0 = b2v[0], p1 = b2v[1], p2 = b2v[2];
    for (int js = 0; js < JS; ++js) {
      const float* pj = pp + ((size_t)js * NVPT + cg) * 3;
      p0 += pj[0]; p1 += pj[1]; p2 += pj[2];
    }
    float val = ws_val[g];
    float4 ai = ws_ai[cg];
    o0 += ai.x * tanhf(p0) * val;
    o1 += ai.y * tanhf(p1) * val;
    o2 += ai.z * tanhf(p2) * val;
  }
  out_pos[(size_t)g * 3 + 0] = o0;
  out_pos[(size_t)g * 3 + 1] = o1;
  out_pos[(size_t)g * 3 + 2] = o2;
}

extern "C" void kernel_launch(void* const* d_in, const int* in_sizes, int n_in,
                              void* d_out, int out_size, void* d_ws, size_t ws_size,
                              hipStream_t stream) {
  const float* bb    = (const float*)d_in[0];
  const float* sf    = (const float*)d_in[1];
  const float* aa    = (const float*)d_in[2];
  const float* mask  = (const float*)d_in[4];
  const float* pm    = (const float*)d_in[5];
  const float* emb   = (const float*)d_in[6];
  const float* W1    = (const float*)d_in[7];
  const float* b1v   = (const float*)d_in[8];
  const float* W2    = (const float*)d_in[9];
  const float* b2v   = (const float*)d_in[10];
  const float* noise = (const float*)d_in[11];

  float* out_mask = (float*)d_out;
  float* out_pos  = (float*)d_out + BB * LL * NAT;

  char* cur = (char*)d_ws;
  auto alloc = [&](size_t bytes) -> char* {
    char* p = cur;
    cur += (bytes + 15) & ~(size_t)15;
    return p;
  };
  float4* ws_xe  = (float4*)alloc((size_t)TOT * 16);
  float*  ws_val = (float*)alloc((size_t)TOT * 4);
  int*    g2cg   = (int*)alloc((size_t)TOT * 4);
  int*    cg2g   = (int*)alloc((size_t)BB * NVP * 4);
  float4* xc     = (float4*)alloc((size_t)BB * NVP * 16);
  float4* ws_ai  = (float4*)alloc((size_t)NVPT * 16);
  float*  ws_dgp = (float*)alloc((size_t)KC * NVPT * 16);
  float*  ws_pp  = (float*)alloc((size_t)JS * NVPT * 12);
  __hip_bfloat16* ws_w1t = (__hip_bfloat16*)alloc((size_t)HID * 256 * 2);
  __hip_bfloat16* hfTc   = (__hip_bfloat16*)alloc((size_t)BB * ADX * NVP * 2);
  __hip_bfloat16* haggp  = (__hip_bfloat16*)alloc((size_t)KC * NVPT * AD * 2);
  __hip_bfloat16* ws_z   = (__hip_bfloat16*)alloc((size_t)NVPT * 256 * 2);

  hipLaunchKernelGGL(k_wprep, dim3(32), dim3(256), 0, stream, W1, ws_w1t);
  hipLaunchKernelGGL(k_prep0, dim3(BB * LL), dim3(64), 0, stream,
                     bb, aa, mask, pm, noise, out_mask, ws_xe, ws_val);
  hipLaunchKernelGGL(k_scan, dim3(BB), dim3(256), 0, stream,
                     ws_val, ws_xe, g2cg, cg2g, xc);
  hipLaunchKernelGGL(k_prep1c, dim3(BB * NVT), dim3(256), 0, stream,
                     sf, emb, ws_val, cg2g, xc, hfTc, ws_z);
  hipLaunchKernelGGL(k_haggc, dim3(BB * NVT * KC), dim3(256), 0, stream,
                     xc, hfTc, haggp, ws_dgp);
  hipLaunchKernelGGL(k_reduce, dim3(NVPT / 16), dim3(256), 0, stream,
                     haggp, ws_dgp, xc, ws_ai, ws_z);
  hipLaunchKernelGGL(k_mlp, dim3((NVPT / 32) * JS), dim3(128), 0, stream,
                     ws_z, ws_w1t, b1v, W2, ws_pp);
  hipLaunchKernelGGL(k_fin, dim3((TOT + 255) / 256), dim3(256), 0, stream,
                     ws_pp, b2v, ws_xe, ws_val, ws_ai, g2cg, out_pos);
}